// Round 6
// baseline (4272.192 us; speedup 1.0000x reference)
//
#include <hip/hip_runtime.h>
#include <hip/hip_bf16.h>
#include <cstddef>

#define D_   1024
#define DI_  2048
#define DS_  16
#define DTR_ 64
#define KC_  4
#define HR_  16
#define DHR_ 64
#define HA_  32
#define DHA_ 32
#define NM_  6
#define NR_  4
#define NT_  2
#define B_   2
#define L_   1024
#define NBL  (B_*L_)   // 2048 rows

typedef __hip_bfloat16 bf16;
typedef __attribute__((ext_vector_type(8))) short short8v;   // 8 bf16 (4 VGPRs)
typedef __attribute__((ext_vector_type(4))) float float4v;   // MFMA C/D frag

__device__ __forceinline__ float bfbits2f(unsigned short u) {
    return __uint_as_float(((unsigned int)u) << 16);
}
__device__ __forceinline__ float b2f(bf16 x) { return __bfloat162float(x); }
__device__ __forceinline__ unsigned short f2bfbits(float f) {
    bf16 h = __float2bfloat16(f);
    return *reinterpret_cast<unsigned short*>(&h);
}
// dtype-dispatched model-input load: bf==1 -> bf16, bf==0 -> fp32
__device__ __forceinline__ float ldf(const void* p, long i, int bf) {
    if (bf) return bfbits2f(((const unsigned short*)p)[i]);
    return ((const float*)p)[i];
}
__device__ __forceinline__ float softplus_f(float x) {
    return x > 20.f ? x : log1pf(__expf(x));
}
__device__ __forceinline__ float silu_f(float x) {
    return x / (1.f + __expf(-x));
}

// ---------------------------------------------------------------------------
// Diagnostic writer (fp32 out): zeros the output, writes a code into out[0].
// ---------------------------------------------------------------------------
__global__ __launch_bounds__(256) void diag_k(float* __restrict__ out, float code)
{
    const int idx = blockIdx.x * 256 + threadIdx.x;
    if (idx < NBL * 3) out[idx] = (idx == 0 ? code : 0.f);
}

// ---------------------------------------------------------------------------
// Input dtype detection (1 wave).
// ---------------------------------------------------------------------------
__global__ __launch_bounds__(64) void detect_k(const void* __restrict__ x,
                                               int* __restrict__ flag)
{
    const unsigned short* u = (const unsigned short*)x;
    int local = 0;
    for (int i = threadIdx.x; i < 1024; i += 64) {
        const float av = fabsf(bfbits2f(u[i]));
        if (!(av < 1e6f)) local = 1;   // catches huge and NaN
    }
    const unsigned long long b = __ballot(local);
    if (threadIdx.x == 0) flag[0] = b ? 0 : 1;  // 1 => inputs are bf16
}

#define BM 64
#define BN 64
#define TK 64
#define LDT 72

// ---------------------------------------------------------------------------
// Big MFMA GEMM: 128-row block tile, BN = NF*32 cols (NF=4 -> 128, NF=2 -> 64).
// 4 waves in 2x2; each wave owns 64 x (BN/2) = 4 x NF fragments of 16x16.
// Per K=64 tile per wave: (4+NF)*2 ds_read_b128 vs 8*NF MFMA (ratio 0.5/0.75
// vs the 64-tile kernel's 1.0 -> less LDS-read-bound).
// Requires M%128==0, K%64==0, N%BN==0 (all big call sites satisfy).
// ---------------------------------------------------------------------------
template<int NF>
__global__ __launch_bounds__(256) void gemm_big_k(
    const void* __restrict__ A, int lda, int aDt,
    const void* __restrict__ W, long woff,
    const void* __restrict__ bias, long boff, int hasBias,
    void* __restrict__ C, int ldc, int cDt,
    int N, int K, int act, int acc,
    const int* __restrict__ flagp)
{
    constexpr int BNt = NF * 32;
    constexpr int BG  = 256 / BNt;     // staging groups: 2 (BN128) or 4 (BN64)
    constexpr int KPT = 64 / BG;       // k rows per staging thread: 32 or 16
    const int bf = *flagp;
    __shared__ short As[128 * LDT];
    __shared__ short Bs[BNt * LDT];
    const int bm = blockIdx.y * 128;
    const int bn = blockIdx.x * BNt;
    const int tid = threadIdx.x;
    const int lane = tid & 63;
    const int wid = tid >> 6;
    const int wr = wid >> 1, wc = wid & 1;

    const int fc  = lane & 15;
    const int g   = lane >> 4;
    const int fk8 = g << 3;

    const int sa_row = tid >> 1;          // 0..127
    const int sa_k   = (tid & 1) << 5;    // 0 / 32

    const int sb_n = tid & (BNt - 1);
    const int sb_k = (tid / BNt) * KPT;

    float4v accv[4][NF] = {};

    for (int k0 = 0; k0 < K; k0 += TK) {
        // ---- stage A tile (128 rows x 64 k), 32 bf16 per thread ----
        if (aDt) {
            const unsigned short* ap = (const unsigned short*)A
                + (size_t)(bm + sa_row) * lda + k0 + sa_k;
            #pragma unroll
            for (int q = 0; q < 4; ++q)
                *(short8v*)&As[sa_row * LDT + sa_k + q * 8] =
                    *(const short8v*)(ap + q * 8);
        } else {
            const float* ap = (const float*)A + (size_t)(bm + sa_row) * lda + k0 + sa_k;
            #pragma unroll
            for (int q = 0; q < 4; ++q) {
                const float4 v0 = *(const float4*)(ap + q * 8);
                const float4 v1 = *(const float4*)(ap + q * 8 + 4);
                short8v t;
                t[0]=(short)f2bfbits(v0.x); t[1]=(short)f2bfbits(v0.y);
                t[2]=(short)f2bfbits(v0.z); t[3]=(short)f2bfbits(v0.w);
                t[4]=(short)f2bfbits(v1.x); t[5]=(short)f2bfbits(v1.y);
                t[6]=(short)f2bfbits(v1.z); t[7]=(short)f2bfbits(v1.w);
                *(short8v*)&As[sa_row * LDT + sa_k + q * 8] = t;
            }
        }
        // ---- stage B tile transposed: Bs[n][k] ----
        {
            const long wbase = woff + (long)(k0 + sb_k) * N + (bn + sb_n);
            short tmp[KPT];
            if (bf) {
                const unsigned short* wp = (const unsigned short*)W;
                #pragma unroll
                for (int j = 0; j < KPT; ++j) tmp[j] = (short)wp[wbase + (long)j * N];
            } else {
                const float* wp = (const float*)W;
                #pragma unroll
                for (int j = 0; j < KPT; ++j) tmp[j] = (short)f2bfbits(wp[wbase + (long)j * N]);
            }
            #pragma unroll
            for (int q = 0; q < KPT / 8; ++q) {
                short8v t;
                #pragma unroll
                for (int e = 0; e < 8; ++e) t[e] = tmp[q * 8 + e];
                *(short8v*)&Bs[sb_n * LDT + sb_k + q * 8] = t;
            }
        }
        __syncthreads();
        // ---- MFMA: 8*NF per wave per K-tile ----
        #pragma unroll
        for (int ks = 0; ks < TK; ks += 32) {
            short8v af[4], bfr[NF];
            #pragma unroll
            for (int mi = 0; mi < 4; ++mi)
                af[mi] = *(const short8v*)&As[(wr * 64 + mi * 16 + fc) * LDT + ks + fk8];
            #pragma unroll
            for (int ni = 0; ni < NF; ++ni)
                bfr[ni] = *(const short8v*)&Bs[(wc * (NF * 16) + ni * 16 + fc) * LDT + ks + fk8];
            #pragma unroll
            for (int mi = 0; mi < 4; ++mi)
                #pragma unroll
                for (int ni = 0; ni < NF; ++ni)
                    accv[mi][ni] = __builtin_amdgcn_mfma_f32_16x16x32_bf16(
                        af[mi], bfr[ni], accv[mi][ni], 0, 0, 0);
        }
        __syncthreads();
    }

    // ---- epilogue: C/D layout col=lane&15, row=(lane>>4)*4+j ----
    const int crow0 = bm + wr * 64 + (g << 2);
    const int ccol0 = bn + wc * (NF * 16) + fc;
    #pragma unroll
    for (int ni = 0; ni < NF; ++ni) {
        const int col = ccol0 + ni * 16;
        if (col < N) {
            const float bsv = hasBias ? ldf(bias, boff + col, bf) : 0.f;
            #pragma unroll
            for (int mi = 0; mi < 4; ++mi) {
                #pragma unroll
                for (int j = 0; j < 4; ++j) {
                    const int row = crow0 + mi * 16 + j;
                    float r = accv[mi][ni][j] + bsv;
                    if (act == 1) r = softplus_f(r);
                    if (cDt) {
                        ((bf16*)C)[(size_t)row * ldc + col] = __float2bfloat16(r);
                    } else {
                        float* cp = (float*)C + (size_t)row * ldc + col;
                        if (acc) r += *cp;
                        *cp = r;
                    }
                }
            }
        }
    }
}

// ---------------------------------------------------------------------------
// Small-N MFMA GEMM (kept for N=96 Wx): tile 64x64, TK=64.
// ---------------------------------------------------------------------------
__global__ __launch_bounds__(256) void gemm_k(
    const void* __restrict__ A, int lda, int aDt,
    const void* __restrict__ W, long woff,
    const void* __restrict__ bias, long boff, int hasBias,
    void* __restrict__ C, int ldc, int cDt,
    int N, int K, int act, int acc,
    const int* __restrict__ flagp)
{
    const int bf = *flagp;
    __shared__ short As[BM * LDT];
    __shared__ short Bs[BN * LDT];
    const int bm = blockIdx.y * BM;
    const int bn = blockIdx.x * BN;
    const int tid = threadIdx.x;
    const int lane = tid & 63;
    const int wid = tid >> 6;
    const int wr = wid >> 1, wc = wid & 1;

    const int sa_row = tid >> 2;            // 0..63
    const int sa_kq  = (tid & 3) << 4;      // 0,16,32,48
    const int sb_col = tid & 63;            // 0..63 (wave-coalesced in n)
    const int sb_kq  = (tid >> 6) << 4;     // 0,16,32,48
    const int sb_gn  = bn + sb_col;

    float4v accv[2][2] = {};

    for (int k0 = 0; k0 < K; k0 += TK) {
        {   // A tile
            short8v a0, a1;
            const size_t aoff = (size_t)(bm + sa_row) * lda + k0 + sa_kq;
            if (aDt) {
                a0 = *(const short8v*)((const unsigned short*)A + aoff);
                a1 = *(const short8v*)((const unsigned short*)A + aoff + 8);
            } else {
                const float* ap = (const float*)A + aoff;
                const float4 v0 = *(const float4*)(ap + 0);
                const float4 v1 = *(const float4*)(ap + 4);
                const float4 v2 = *(const float4*)(ap + 8);
                const float4 v3 = *(const float4*)(ap + 12);
                a0[0]=f2bfbits(v0.x); a0[1]=f2bfbits(v0.y); a0[2]=f2bfbits(v0.z); a0[3]=f2bfbits(v0.w);
                a0[4]=f2bfbits(v1.x); a0[5]=f2bfbits(v1.y); a0[6]=f2bfbits(v1.z); a0[7]=f2bfbits(v1.w);
                a1[0]=f2bfbits(v2.x); a1[1]=f2bfbits(v2.y); a1[2]=f2bfbits(v2.z); a1[3]=f2bfbits(v2.w);
                a1[4]=f2bfbits(v3.x); a1[5]=f2bfbits(v3.y); a1[6]=f2bfbits(v3.z); a1[7]=f2bfbits(v3.w);
            }
            *(short8v*)&As[sa_row * LDT + sa_kq + 0] = a0;
            *(short8v*)&As[sa_row * LDT + sa_kq + 8] = a1;
        }
        {   // B tile transposed
            short8v b0, b1;
            #pragma unroll
            for (int j = 0; j < 8; ++j) { b0[j] = 0; b1[j] = 0; }
            if (sb_gn < N) {
                const long wbase = woff + (long)(k0 + sb_kq) * N + sb_gn;
                if (bf) {
                    const unsigned short* wp = (const unsigned short*)W;
                    #pragma unroll
                    for (int j = 0; j < 8; ++j) {
                        b0[j] = (short)wp[wbase + (long)j * N];
                        b1[j] = (short)wp[wbase + (long)(j + 8) * N];
                    }
                } else {
                    const float* wp = (const float*)W;
                    #pragma unroll
                    for (int j = 0; j < 8; ++j) {
                        b0[j] = (short)f2bfbits(wp[wbase + (long)j * N]);
                        b1[j] = (short)f2bfbits(wp[wbase + (long)(j + 8) * N]);
                    }
                }
            }
            *(short8v*)&Bs[sb_col * LDT + sb_kq + 0] = b0;
            *(short8v*)&Bs[sb_col * LDT + sb_kq + 8] = b1;
        }
        __syncthreads();
        {
            const int r  = lane & 15;
            const int kb = (lane >> 4) << 3;   // 0,8,16,24
            #pragma unroll
            for (int ks = 0; ks < TK; ks += 32) {
                const int kg = ks + kb;
                const short8v a0 = *(const short8v*)&As[(wr*32 +      r) * LDT + kg];
                const short8v a1 = *(const short8v*)&As[(wr*32 + 16 + r) * LDT + kg];
                const short8v b0 = *(const short8v*)&Bs[(wc*32 +      r) * LDT + kg];
                const short8v b1 = *(const short8v*)&Bs[(wc*32 + 16 + r) * LDT + kg];
                accv[0][0] = __builtin_amdgcn_mfma_f32_16x16x32_bf16(a0, b0, accv[0][0], 0, 0, 0);
                accv[0][1] = __builtin_amdgcn_mfma_f32_16x16x32_bf16(a0, b1, accv[0][1], 0, 0, 0);
                accv[1][0] = __builtin_amdgcn_mfma_f32_16x16x32_bf16(a1, b0, accv[1][0], 0, 0, 0);
                accv[1][1] = __builtin_amdgcn_mfma_f32_16x16x32_bf16(a1, b1, accv[1][1], 0, 0, 0);
            }
        }
        __syncthreads();
    }

    const int crow0 = bm + wr * 32 + ((lane >> 4) << 2);
    const int ccol0 = bn + wc * 32 + (lane & 15);
    #pragma unroll
    for (int ni = 0; ni < 2; ++ni) {
        const int col = ccol0 + ni * 16;
        if (col < N) {
            const float bsv = hasBias ? ldf(bias, boff + col, bf) : 0.f;
            #pragma unroll
            for (int mi = 0; mi < 2; ++mi) {
                #pragma unroll
                for (int j = 0; j < 4; ++j) {
                    const int row = crow0 + mi * 16 + j;
                    float r = accv[mi][ni][j] + bsv;
                    if (act == 1) r = softplus_f(r);
                    if (cDt) {
                        ((bf16*)C)[(size_t)row * ldc + col] = __float2bfloat16(r);
                    } else {
                        float* cp = (float*)C + (size_t)row * ldc + col;
                        if (acc) r += *cp;
                        *cp = r;
                    }
                }
            }
        }
    }
}

// ---------------------------------------------------------------------------
__global__ __launch_bounds__(256) void cast3_k(const void* __restrict__ x,
    float* __restrict__ a, float* __restrict__ b, float* __restrict__ c,
    const int* __restrict__ flagp)
{
    const int bf = *flagp;
    const int idx = blockIdx.x * 256 + threadIdx.x;
    const float v = ldf(x, idx, bf);
    a[idx] = v; b[idx] = v; c[idx] = v;
}

// ---------------------------------------------------------------------------
__global__ __launch_bounds__(256) void rmsnorm_k(const float* __restrict__ x,
    const void* __restrict__ wgt, long woff, float* __restrict__ out,
    const int* __restrict__ flagp)
{
    const int bf = *flagp;
    const int row = blockIdx.x;
    const float* xr = x + (size_t)row * D_;
    float ss = 0.f;
    for (int i = threadIdx.x; i < D_; i += 256) { const float v = xr[i]; ss = fmaf(v, v, ss); }
    #pragma unroll
    for (int msk = 1; msk < 64; msk <<= 1) ss += __shfl_xor(ss, msk);
    __shared__ float red[4];
    if ((threadIdx.x & 63) == 0) red[threadIdx.x >> 6] = ss;
    __syncthreads();
    ss = red[0] + red[1] + red[2] + red[3];
    const float scale = rsqrtf(ss * (1.f / D_) + 1e-6f);
    float* orow = out + (size_t)row * D_;
    for (int i = threadIdx.x; i < D_; i += 256)
        orow[i] = xr[i] * scale * ldf(wgt, woff + i, bf);
}

// ---------------------------------------------------------------------------
// Depthwise causal conv (K=4) + SiLU. xc = cols [0,DI) of xz16 (stride 2*DI).
// ---------------------------------------------------------------------------
__global__ __launch_bounds__(256) void conv_silu_k(const bf16* __restrict__ xz,
    const void* __restrict__ cw, long cwoff, const void* __restrict__ cb, long cboff,
    bf16* __restrict__ out, const int* __restrict__ flagp)
{
    const int bf = *flagp;
    const int idx = blockIdx.x * 256 + threadIdx.x;
    const int c = idx & (DI_ - 1);
    const int l = (idx >> 11) & (L_ - 1);
    const int b = idx >> 21;
    float acc = ldf(cb, cboff + c, bf);
    #pragma unroll
    for (int j = 0; j < KC_; ++j) {
        const int ls = l - (KC_ - 1) + j;
        if (ls >= 0)
            acc = fmaf(b2f(xz[((size_t)(b * L_ + ls)) * (2 * DI_) + c]),
                       ldf(cw, cwoff + j * DI_ + c, bf), acc);
    }
    out[idx] = __float2bfloat16(silu_f(acc));
}

// ---------------------------------------------------------------------------
// Mamba selective scan — chunk-parallel + XCD swizzle (see round 5 notes).
// ---------------------------------------------------------------------------
#define MS_NCH 16
#define MS_CH  (L_ / MS_NCH)   // 64

__global__ __launch_bounds__(256) void mamba_scan_k(
    const bf16* __restrict__ u, const bf16* __restrict__ dlt,
    const float* __restrict__ xdbl, bf16* __restrict__ xz,
    const void* __restrict__ Alog, long aoff, const void* __restrict__ Dp, long doff,
    const int* __restrict__ flagp)
{
    const int bf = *flagp;
    const int bid = ((blockIdx.x & 7) << 9) | (blockIdx.x >> 3);  // XCD swizzle, B*DI = 4096
    const int d = bid & (DI_ - 1);
    const int b = bid >> 11;
    const int s = threadIdx.x & (DS_ - 1);
    const int c = threadIdx.x >> 4;        // chunk 0..15
    const float Av = -__expf(ldf(Alog, aoff + d * DS_ + s, bf));
    const float Dv = ldf(Dp, doff + d, bf);

    __shared__ float Pl[MS_NCH][DS_];
    __shared__ float Sl[MS_NCH][DS_];

    const int l0 = c * MS_CH;

    // pass 1: chunk-local (P, S)
    float P = 1.f, S = 0.f;
    for (int i = 0; i < MS_CH; ++i) {
        const size_t row = (size_t)(b * L_ + l0 + i);
        const float ut = b2f(u[row * DI_ + d]);
        const float dt = b2f(dlt[row * DI_ + d]);
        const float Bv = xdbl[row * 96 + 64 + s];
        const float dA = __expf(dt * Av);
        P *= dA;
        S = fmaf(S, dA, dt * ut * Bv);
    }
    Pl[c][s] = P; Sl[c][s] = S;
    __syncthreads();

    // prefix combine: h at this chunk's start
    float hs = 0.f;
    for (int cc = 0; cc < c; ++cc) hs = fmaf(hs, Pl[cc][s], Sl[cc][s]);

    // pass 2: rescan with true h0, reduce over s, write y
    for (int i = 0; i < MS_CH; ++i) {
        const size_t row = (size_t)(b * L_ + l0 + i);
        const float ut = b2f(u[row * DI_ + d]);
        const float dt = b2f(dlt[row * DI_ + d]);
        const float Bv = xdbl[row * 96 + 64 + s];
        const float Cv = xdbl[row * 96 + 80 + s];
        const float dA = __expf(dt * Av);
        hs = fmaf(hs, dA, dt * ut * Bv);
        float yp = hs * Cv;
        yp += __shfl_xor(yp, 1, 16);
        yp += __shfl_xor(yp, 2, 16);
        yp += __shfl_xor(yp, 4, 16);
        yp += __shfl_xor(yp, 8, 16);
        if (s == 0) {
            const float z = b2f(xz[row * (2 * DI_) + DI_ + d]);
            xz[row * (2 * DI_) + d] = __float2bfloat16((yp + Dv * ut) * silu_f(z));
        }
    }
}

// ---------------------------------------------------------------------------
__global__ __launch_bounds__(256) void rwkv_mix_k(const float* __restrict__ xn,
    const void* __restrict__ mu, long muoff, bf16* __restrict__ o0,
    bf16* __restrict__ o1, bf16* __restrict__ o2, const int* __restrict__ flagp)
{
    const int bf = *flagp;
    const int idx = blockIdx.x * 256 + threadIdx.x;
    const int d = idx & (D_ - 1);
    const int l = (idx >> 10) & (L_ - 1);
    const float cur = xn[idx];
    const float prev = (l > 0) ? xn[idx - D_] : 0.f;
    const float m0 = ldf(mu, muoff + d, bf);
    const float m1 = ldf(mu, muoff + D_ + d, bf);
    const float m2 = ldf(mu, muoff + 2 * D_ + d, bf);
    o0[idx] = __float2bfloat16(cur * m0 + prev * (1.f - m0));
    o1[idx] = __float2bfloat16(cur * m1 + prev * (1.f - m1));
    o2[idx] = __float2bfloat16(cur * m2 + prev * (1.f - m2));
}

// ---------------------------------------------------------------------------
// RWKV scan — chunk-parallel + XCD swizzle (see round 5 notes).
// ---------------------------------------------------------------------------
#define RW_NCH 16
#define RW_CH  (L_ / RW_NCH)   // 64

__global__ __launch_bounds__(1024) void rwkv_scan_k(const bf16* __restrict__ R,
    const bf16* __restrict__ Kb, const bf16* __restrict__ V,
    const void* __restrict__ wlog, long woff, const void* __restrict__ uu, long uoff,
    bf16* __restrict__ Y, const int* __restrict__ flagp)
{
    const int bf = *flagp;
    const int bid = ((blockIdx.x & 7) << 8) | (blockIdx.x >> 3);  // XCD swizzle, B*HR*DHR = 2048
    const int v = bid & (DHR_ - 1);
    const int h = (bid >> 6) & (HR_ - 1);
    const int b = bid >> 10;
    const int k = threadIdx.x & 63;
    const int c = threadIdx.x >> 6;       // chunk 0..15
    const float ew = __expf(ldf(wlog, woff + h * DHR_ + k, bf));
    const float w  = __expf(-ew);
    const float wC = __expf(-ew * (float)RW_CH);   // w^CH
    const float uv = ldf(uu, uoff + h * DHR_ + k, bf);

    __shared__ float Se[RW_NCH][64];

    const int l0 = c * RW_CH;

    // pass 1: chunk-local S_end (S0 = 0)
    float S = 0.f;
    for (int i = 0; i < RW_CH; ++i) {
        const size_t off = ((size_t)(b * L_ + l0 + i)) * D_ + h * DHR_;
        const float kk = b2f(Kb[off + k]);
        const float vt = b2f(V[off + v]);
        S = fmaf(w, S, kk * vt);
    }
    Se[c][k] = S;
    __syncthreads();

    // prefix: S at this chunk's start
    S = 0.f;
    for (int cc = 0; cc < c; ++cc) S = fmaf(wC, S, Se[cc][k]);

    // pass 2: rescan with true S0, reduce over k, write y
    for (int i = 0; i < RW_CH; ++i) {
        const size_t off = ((size_t)(b * L_ + l0 + i)) * D_ + h * DHR_;
        const float r  = b2f(R[off + k]);
        const float kk = b2f(Kb[off + k]);
        const float vt = b2f(V[off + v]);
        const float kv = kk * vt;
        float yp = r * fmaf(uv, kv, S);
        S = fmaf(w, S, kv);
        yp += __shfl_xor(yp, 1);
        yp += __shfl_xor(yp, 2);
        yp += __shfl_xor(yp, 4);
        yp += __shfl_xor(yp, 8);
        yp += __shfl_xor(yp, 16);
        yp += __shfl_xor(yp, 32);
        if (k == 0) Y[off + v] = __float2bfloat16(yp);
    }
}

// ---------------------------------------------------------------------------
// MHA flash attention — MFMA version (see round 4 notes).
// ---------------------------------------------------------------------------
#define LDK 40   // Ks row pitch (bf16): 80B, 16B-aligned, 2-way banks (free)
#define LDV 72   // Vt/Ps row pitch (bf16): 144B, 16B-aligned, 2-way banks

__global__ __launch_bounds__(256) void mha_attn_k(const bf16* __restrict__ Q,
    const bf16* __restrict__ Kx, const bf16* __restrict__ V, bf16* __restrict__ O)
{
    const int b = blockIdx.z, h = blockIdx.y;
    const int qt = blockIdx.x;            // 0..15
    const int tid = threadIdx.x;
    const int lane = tid & 63;
    const int wid = tid >> 6;

    __shared__ __align__(16) short Ks[64 * LDK];
    __shared__ __align__(16) short Vt[32 * LDV];
    __shared__ __align__(16) short Ps[4][16 * LDV];

    const int fc  = lane & 15;            // A-row / B-col within fragment
    const int g   = lane >> 4;            // k-octet group; C rows = g*4+j
    const int fk8 = g << 3;               // 0,8,16,24

    const int q0 = qt * 64 + wid * 16;

    // Q fragment (K=32 = full head dim), loaded once
    const size_t qoff = ((size_t)(b * L_ + q0 + fc)) * D_ + h * DHA_ + fk8;
    const short8v qf = *(const short8v*)((const unsigned short*)Q + qoff);

    float4v o0 = {}, o1 = {};
    float m[4] = {-1e30f, -1e30f, -1e30f, -1e30f};
    float l[4] = {0.f, 0.f, 0.f, 0.f};
    const float scale = 0.1767766952966369f;   // 1/sqrt(32)

    // staging indices: thread t covers (row=t>>2, d-octet=(t&3)*8)
    const int sr = tid >> 2;
    const int sc = (tid & 3) << 3;

    for (int kt = 0; kt < L_; kt += 64) {
        __syncthreads();   // all waves done reading previous Ks/Vt
        {
            const size_t koff = ((size_t)(b * L_ + kt + sr)) * D_ + h * DHA_ + sc;
            const short8v k8 = *(const short8v*)((const unsigned short*)Kx + koff);
            *(short8v*)&Ks[sr * LDK + sc] = k8;
            const short8v v8 = *(const short8v*)((const unsigned short*)V + koff);
            #pragma unroll
            for (int j = 0; j < 8; ++j)
                Vt[(sc + j) * LDV + sr] = v8[j];
        }
        __syncthreads();

        // ---- QK^T: 4 mfma over 4 kv-16 sub-tiles ----
        float4v sv[4];
        #pragma unroll
        for (int nt = 0; nt < 4; ++nt) {
            const short8v kf = *(const short8v*)&Ks[(nt * 16 + fc) * LDK + fk8];
            float4v z = {};
            sv[nt] = __builtin_amdgcn_mfma_f32_16x16x32_bf16(qf, kf, z, 0, 0, 0);
        }

        // ---- online softmax (rows g*4+j, cols nt*16+fc) ----
        #pragma unroll
        for (int j = 0; j < 4; ++j) {
            float mt = fmaxf(fmaxf(sv[0][j], sv[1][j]), fmaxf(sv[2][j], sv[3][j])) * scale;
            #pragma unroll
            for (int msk = 1; msk < 16; msk <<= 1) mt = fmaxf(mt, __shfl_xor(mt, msk));
            const float mn = fmaxf(m[j], mt);
            const float corr = __expf(m[j] - mn);
            m[j] = mn;
            float sum = 0.f;
            #pragma unroll
            for (int nt = 0; nt < 4; ++nt) {
                const float p = __expf(fmaf(sv[nt][j], scale, -mn));
                sum += p;
                Ps[wid][(g * 4 + j) * LDV + nt * 16 + fc] = (short)f2bfbits(p);
            }
            #pragma unroll
            for (int msk = 1; msk < 16; msk <<= 1) sum += __shfl_xor(sum, msk);
            l[j] = l[j] * corr + sum;
            o0[j] *= corr;
            o1[j] *= corr;
        }

        // ---- PV: O += P(16x64) . V(64x32), 2 k-chunks x 2 d-tiles ----
        #pragma unroll
        for (int kc = 0; kc < 2; ++kc) {
            const short8v pf = *(const short8v*)&Ps[wid][fc * LDV + kc * 32 + fk8];
            const short8v v0 = *(const short8v*)&Vt[(fc) * LDV + kc * 32 + fk8];
            const short8v v1 = *(const short8v*)&Vt[(16 + fc) * LDV + kc * 32 + fk8];
            o0 = __builtin_amdgcn_mfma_f32_16x16x32_bf16(pf, v0, o0, 0, 0, 0);
            o1 = __builtin_amdgcn_mfma_f32_16x16x32_bf16(pf, v1, o1, 0, 0, 0);
        }
    }

    // ---- epilogue ----
    #pragma unroll
    for (int j = 0; j < 4; ++j) {
        const float inv = 1.f / l[j];
        const size_t ooff = ((size_t)(b * L_ + q0 + g * 4 + j)) * D_ + h * DHA_;
        O[ooff + fc]      = __float2bfloat16(o0[j] * inv);
        O[ooff + 16 + fc] = __float2bfloat16(o1[j] * inv);
    }
}

// ---------------------------------------------------------------------------
// Final: logits = [m,r,t] @ f_W + f_b; softmax over 3; fp32 out.
// ---------------------------------------------------------------------------
__global__ __launch_bounds__(256) void final_k(const float* __restrict__ m,
    const float* __restrict__ r, const float* __restrict__ t,
    const void* __restrict__ fW, const void* __restrict__ fb,
    float* __restrict__ out, const int* __restrict__ flagp)
{
    const int bf = *flagp;
    const int row = blockIdx.x;
    float p0 = 0.f, p1 = 0.f, p2 = 0.f;
    for (int i = threadIdx.x; i < 3 * D_; i += 256) {
        float v;
        if (i < D_)          v = m[(size_t)row * D_ + i];
        else if (i < 2 * D_) v = r[(size_t)row * D_ + i - D_];
        else                 v = t[(size_t)row * D_ + i - 2 * D_];
        p0 = fmaf(v, ldf(fW, (long)i * 3 + 0, bf), p0);
        p1 = fmaf(v, ldf(fW, (long)i * 3 + 1, bf), p1);
        p2 = fmaf(v, ldf(fW, (long)i * 3 + 2, bf), p2);
    }
    #pragma unroll
    for (int msk = 1; msk < 64; msk <<= 1) {
        p0 += __shfl_xor(p0, msk);
        p1 += __shfl_xor(p1, msk);
        p2 += __shfl_xor(p2, msk);
    }
    __shared__ float red[4][3];
    if ((threadIdx.x & 63) == 0) {
        const int w = threadIdx.x >> 6;
        red[w][0] = p0; red[w][1] = p1; red[w][2] = p2;
    }
    __syncthreads();
    if (threadIdx.x == 0) {
        const float l0 = red[0][0] + red[1][0] + red[2][0] + red[3][0] + ldf(fb, 0, bf);
        const float l1 = red[0][1] + red[1][1] + red[2][1] + red[3][1] + ldf(fb, 1, bf);
        const float l2 = red[0][2] + red[1][2] + red[2][2] + red[3][2] + ldf(fb, 2, bf);
        const float mx = fmaxf(l0, fmaxf(l1, l2));
        const float e0 = __expf(l0 - mx), e1 = __expf(l1 - mx), e2 = __expf(l2 - mx);
        const float inv = 1.f / (e0 + e1 + e2);
        out[row * 3 + 0] = e0 * inv;
        out[row * 3 + 1] = e1 * inv;
        out[row * 3 + 2] = e2 * inv;
    }
}

// ---------------------------------------------------------------------------
extern "C" void kernel_launch(void* const* d_in, const int* in_sizes, int n_in,
                              void* d_out, int out_size, void* d_ws, size_t ws_size,
                              hipStream_t stream)
{
    float* out = (float*)d_out;

    // ---- self-diagnosis: verify input sizes (dict order) -------------------
    static const int expected[29] = {
        2097152, 6144, 25165824, 49152, 12288, 1179648, 786432, 12288,
        196608, 12288, 12582912, 4096, 12288, 4194304, 4194304, 4194304,
        4194304, 4096, 4096, 2097152, 2048, 2097152, 2048, 2097152, 2048,
        2097152, 2048, 9216, 3 };
    int bad = (n_in == 29) ? -1 : 29;
    if (bad < 0)
        for (int i = 0; i < 29; ++i)
            if (in_sizes[i] != expected[i]) { bad = i; break; }
    if (bad >= 0) {
        diag_k<<<24, 256, 0, stream>>>(out, 1000.f + 8.f * bad);
        return;
    }

    // ---- workspace layout (56.8 MB total) ----------------------------------
    const size_t REQ = 64 + 3ull * 8388608 + 8388608 + 16777216 + 8388608 + 786432;
    if (ws_size < REQ) {
        diag_k<<<24, 256, 0, stream>>>(out, 2048.f + (float)(ws_size >> 20));
        return;
    }
    char* base = (char*)d_ws;
    int*   flag = (int*)base;
    float* resM = (float*)(base + 64);
    float* resR = resM + 2097152;
    float* resT = resR + 2097152;
    float* bufN = resT + 2097152;                 // fp32 xn (NBL*D) / bf16 delta (NBL*DI)
    bf16*  XZ16 = (bf16*)(bufN + 2097152);        // NBL*4096
    bf16*  U16  = XZ16 + (size_t)NBL * 4096;      // NBL*2048
    float* XD   = (float*)(U16 + (size_t)NBL * 2048); // NBL*96

    // quarter views of XZ16 (NBL*1024 each, contiguous)
    bf16* q0 = XZ16;
    bf16* q1 = XZ16 + 1 * 2097152;
    bf16* q2 = XZ16 + 2 * 2097152;
    bf16* q3 = XZ16 + 3 * 2097152;
    bf16* u0 = U16;
    bf16* u1 = U16 + 2097152;

    const void* x        = d_in[0];
    const void* m_norm   = d_in[1];
    const void* m_Win    = d_in[2];
    const void* m_conv_w = d_in[3];
    const void* m_conv_b = d_in[4];
    const void* m_Wx     = d_in[5];
    const void* m_Wdt    = d_in[6];
    const void* m_bdt    = d_in[7];
    const void* m_Alog   = d_in[8];
    const void* m_D      = d_in[9];
    const void* m_Wout   = d_in[10];
    const void* r_norm   = d_in[11];
    const void* r_mu     = d_in[12];
    const void* r_Wr     = d_in[13];
    const void* r_Wk     = d_in[14];
    const void* r_Wv     = d_in[15];
    const void* r_Wo     = d_in[16];
    const void* r_wlog   = d_in[17];
    const void* r_u      = d_in[18];
    const void* a_Wq     = d_in[19];
    const void* a_bq     = d_in[20];
    const void* a_Wk     = d_in[21];
    const void* a_bk     = d_in[22];
    const void* a_Wv     = d_in[23];
    const void* a_bv     = d_in[24];
    const void* a_Wo     = d_in[25];
    const void* a_bo     = d_in[26];
    const void* f_W      = d_in[27];
    const void* f_b      = d_in[28];

    auto gemm = [&](const void* A, int lda, int aDt, const void* W, long woff,
                    const void* bias, long boff, int hasBias,
                    void* C, int ldc, int cDt, int N, int K, int act, int acc) {
        if ((N & 127) == 0 && N >= 2048 && (K & 63) == 0) {
            dim3 g(N / 128, NBL / 128);
            gemm_big_k<4><<<g, 256, 0, stream>>>(A, lda, aDt, W, woff, bias, boff,
                hasBias, C, ldc, cDt, N, K, act, acc, flag);
        } else if ((N & 63) == 0 && (K & 63) == 0) {
            dim3 g(N / 64, NBL / 128);
            gemm_big_k<2><<<g, 256, 0, stream>>>(A, lda, aDt, W, woff, bias, boff,
                hasBias, C, ldc, cDt, N, K, act, acc, flag);
        } else {
            dim3 g((N + BN - 1) / BN, NBL / BM);
            gemm_k<<<g, 256, 0, stream>>>(A, lda, aDt, W, woff, bias, boff, hasBias,
                                          C, ldc, cDt, N, K, act, acc, flag);
        }
    };

    detect_k<<<1, 64, 0, stream>>>(x, flag);
    cast3_k<<<8192, 256, 0, stream>>>(x, resM, resR, resT, flag);

    // ---------------- Mamba branch ----------------
    for (int i = 0; i < NM_; ++i) {
        rmsnorm_k<<<NBL, 256, 0, stream>>>(resM, m_norm, (long)i * D_, bufN, flag);
        gemm(bufN, D_, 0, m_Win, (long)i * D_ * 2 * DI_, nullptr, 0, 0,
             XZ16, 2 * DI_, 1, 2 * DI_, D_, 0, 0);
        conv_silu_k<<<16384, 256, 0, stream>>>(XZ16, m_conv_w, (long)i * KC_ * DI_,
                                               m_conv_b, (long)i * DI_, U16, flag);
        gemm(U16, DI_, 1, m_Wx, (long)i * DI_ * 96, nullptr, 0, 0,
             XD, 96, 0, 96, DI_, 0, 0);
        gemm(XD, 96, 0, m_Wdt, (long)i * DTR_ * DI_, m_bdt, (long)i * DI_, 1,
             bufN, DI_, 1, DI_, DTR_, 1 /*softplus*/, 0);
        mamba_scan_k<<<B_ * DI_, 256, 0, stream>>>(U16, (const bf16*)bufN, XD, XZ16,
            m_Alog, (long)i * DI_ * DS_, m_D, (long)i * DI_, flag);
        gemm(XZ16, 2 * DI_, 1, m_Wout, (long)i * DI_ * D_, nullptr, 0, 0,
             resM, D_, 0, D_, DI_, 0, 1 /*acc*/);
    }

    // ---------------- RWKV branch ----------------
    for (int i = 0; i < NR_; ++i) {
        rmsnorm_k<<<NBL, 256, 0, stream>>>(resR, r_norm, (long)i * D_, bufN, flag);
        rwkv_mix_k<<<8192, 256, 0, stream>>>(bufN, r_mu, (long)i * 3 * D_,
                                             q0, q1, q2, flag);
        gemm(q0, D_, 1, r_Wr, (long)i * D_ * D_, nullptr, 0, 0, u0, D_, 1, D_, D_, 0, 0);
        gemm(q1, D_, 1, r_Wk, (long)i * D_ * D_, nullptr, 0, 0, u1, D_, 1, D_, D_, 0, 0);
        gemm(q2, D_, 1, r_Wv, (long)i * D_ * D_, nullptr, 0, 0, q3, D_, 1, D_, D_, 0, 0);
        rwkv_scan_k<<<B_ * HR_ * DHR_, RW_NCH * 64, 0, stream>>>(u0, u1, q3,
            r_wlog, (long)i * HR_ * DHR_, r_u, (long)i * HR_ * DHR_, q0, flag);
        gemm(q0, D_, 1, r_Wo, (long)i * D_ * D_, nullptr, 0, 0, resR, D_, 0, D_, D_, 0, 1);
    }

    // ---------------- MHA branch (no norm, no residual) ----------------
    for (int i = 0; i < NT_; ++i) {
        gemm(resT, D_, 0, a_Wq, (long)i * D_ * HA_ * DHA_, a_bq, (long)i * HA_ * DHA_, 1,
             u0, D_, 1, D_, D_, 0, 0);
        gemm(resT, D_, 0, a_Wk, (long)i * D_ * HA_ * DHA_, a_bk, (long)i * HA_ * DHA_, 1,
             u1, D_, 1, D_, D_, 0, 0);
        gemm(resT, D_, 0, a_Wv, (long)i * D_ * HA_ * DHA_, a_bv, (long)i * HA_ * DHA_, 1,
             q3, D_, 1, D_, D_, 0, 0);
        mha_attn_k<<<dim3(L_ / 64, HA_, B_), 256, 0, stream>>>(u0, u1, q3, q0);
        gemm(q0, D_, 1, a_Wo, (long)i * HA_ * DHA_ * D_, a_bo, (long)i * D_, 1,
             resT, D_, 0, D_, HA_ * DHA_, 0, 0 /*no residual*/);
    }

    // ---------------- combine + softmax ----------------
    final_k<<<NBL, 256, 0, stream>>>(resM, resR, resT, f_W, f_b, out, flag);
}

// Round 7
// 4085.626 us; speedup vs baseline: 1.0457x; 1.0457x over previous
//
#include <hip/hip_runtime.h>
#include <hip/hip_bf16.h>
#include <cstddef>

#define D_   1024
#define DI_  2048
#define DS_  16
#define DTR_ 64
#define KC_  4
#define HR_  16
#define DHR_ 64
#define HA_  32
#define DHA_ 32
#define NM_  6
#define NR_  4
#define NT_  2
#define B_   2
#define L_   1024
#define NBL  (B_*L_)   // 2048 rows

typedef __hip_bfloat16 bf16;
typedef __attribute__((ext_vector_type(8))) short short8v;   // 8 bf16 (4 VGPRs)
typedef __attribute__((ext_vector_type(4))) float float4v;   // MFMA C/D frag

__device__ __forceinline__ float bfbits2f(unsigned short u) {
    return __uint_as_float(((unsigned int)u) << 16);
}
__device__ __forceinline__ float b2f(bf16 x) { return __bfloat162float(x); }
__device__ __forceinline__ unsigned short f2bfbits(float f) {
    bf16 h = __float2bfloat16(f);
    return *reinterpret_cast<unsigned short*>(&h);
}
// dtype-dispatched model-input load: bf==1 -> bf16, bf==0 -> fp32
__device__ __forceinline__ float ldf(const void* p, long i, int bf) {
    if (bf) return bfbits2f(((const unsigned short*)p)[i]);
    return ((const float*)p)[i];
}
__device__ __forceinline__ float softplus_f(float x) {
    return x > 20.f ? x : log1pf(__expf(x));
}
__device__ __forceinline__ float silu_f(float x) {
    return x / (1.f + __expf(-x));
}

// ---------------------------------------------------------------------------
// Diagnostic writer (fp32 out): zeros the output, writes a code into out[0].
// ---------------------------------------------------------------------------
__global__ __launch_bounds__(256) void diag_k(float* __restrict__ out, float code)
{
    const int idx = blockIdx.x * 256 + threadIdx.x;
    if (idx < NBL * 3) out[idx] = (idx == 0 ? code : 0.f);
}

// ---------------------------------------------------------------------------
// Input dtype detection (1 wave).
// ---------------------------------------------------------------------------
__global__ __launch_bounds__(64) void detect_k(const void* __restrict__ x,
                                               int* __restrict__ flag)
{
    const unsigned short* u = (const unsigned short*)x;
    int local = 0;
    for (int i = threadIdx.x; i < 1024; i += 64) {
        const float av = fabsf(bfbits2f(u[i]));
        if (!(av < 1e6f)) local = 1;   // catches huge and NaN
    }
    const unsigned long long b = __ballot(local);
    if (threadIdx.x == 0) flag[0] = b ? 0 : 1;  // 1 => inputs are bf16
}

#define BM 64
#define BN 64
#define TK 64
#define LDT 72

// ---------------------------------------------------------------------------
// Big MFMA GEMM: 128x128 tile, only for N >= 2048 (keeps grid >= 512 blocks).
// 4 waves in 2x2; each wave owns 64x64 = 4x4 fragments of 16x16.
// Per K=64 tile per wave: 16 ds_read_b128 vs 32 MFMA (ratio 0.5 vs the
// 64-tile kernel's 1.0).  N=1024 call sites stay on gemm_k: routing them
// here (grid 256 = 1 block/CU) was a measured regression (round 6).
// ---------------------------------------------------------------------------
__global__ __launch_bounds__(256) void gemm_big_k(
    const void* __restrict__ A, int lda, int aDt,
    const void* __restrict__ W, long woff,
    const void* __restrict__ bias, long boff, int hasBias,
    void* __restrict__ C, int ldc, int cDt,
    int N, int K, int act, int acc,
    const int* __restrict__ flagp)
{
    const int bf = *flagp;
    __shared__ short As[128 * LDT];
    __shared__ short Bs[128 * LDT];
    const int bm = blockIdx.y * 128;
    const int bn = blockIdx.x * 128;
    const int tid = threadIdx.x;
    const int lane = tid & 63;
    const int wid = tid >> 6;
    const int wr = wid >> 1, wc = wid & 1;

    const int fc  = lane & 15;
    const int g   = lane >> 4;
    const int fk8 = g << 3;

    const int sa_row = tid >> 1;          // 0..127
    const int sa_k   = (tid & 1) << 5;    // 0 / 32

    const int sb_n = tid & 127;           // 0..127
    const int sb_k = (tid >> 7) << 5;     // 0 / 32

    float4v accv[4][4] = {};

    for (int k0 = 0; k0 < K; k0 += TK) {
        // ---- stage A tile (128 rows x 64 k), 32 bf16 per thread ----
        if (aDt) {
            const unsigned short* ap = (const unsigned short*)A
                + (size_t)(bm + sa_row) * lda + k0 + sa_k;
            #pragma unroll
            for (int q = 0; q < 4; ++q)
                *(short8v*)&As[sa_row * LDT + sa_k + q * 8] =
                    *(const short8v*)(ap + q * 8);
        } else {
            const float* ap = (const float*)A + (size_t)(bm + sa_row) * lda + k0 + sa_k;
            #pragma unroll
            for (int q = 0; q < 4; ++q) {
                const float4 v0 = *(const float4*)(ap + q * 8);
                const float4 v1 = *(const float4*)(ap + q * 8 + 4);
                short8v t;
                t[0]=(short)f2bfbits(v0.x); t[1]=(short)f2bfbits(v0.y);
                t[2]=(short)f2bfbits(v0.z); t[3]=(short)f2bfbits(v0.w);
                t[4]=(short)f2bfbits(v1.x); t[5]=(short)f2bfbits(v1.y);
                t[6]=(short)f2bfbits(v1.z); t[7]=(short)f2bfbits(v1.w);
                *(short8v*)&As[sa_row * LDT + sa_k + q * 8] = t;
            }
        }
        // ---- stage B tile transposed: Bs[n][k], 32 k rows per thread ----
        {
            const long wbase = woff + (long)(k0 + sb_k) * N + (bn + sb_n);
            short tmp[32];
            if (bf) {
                const unsigned short* wp = (const unsigned short*)W;
                #pragma unroll
                for (int j = 0; j < 32; ++j) tmp[j] = (short)wp[wbase + (long)j * N];
            } else {
                const float* wp = (const float*)W;
                #pragma unroll
                for (int j = 0; j < 32; ++j) tmp[j] = (short)f2bfbits(wp[wbase + (long)j * N]);
            }
            #pragma unroll
            for (int q = 0; q < 4; ++q) {
                short8v t;
                #pragma unroll
                for (int e = 0; e < 8; ++e) t[e] = tmp[q * 8 + e];
                *(short8v*)&Bs[sb_n * LDT + sb_k + q * 8] = t;
            }
        }
        __syncthreads();
        // ---- MFMA: 32 per wave per K-tile ----
        #pragma unroll
        for (int ks = 0; ks < TK; ks += 32) {
            short8v af[4], bfr[4];
            #pragma unroll
            for (int mi = 0; mi < 4; ++mi)
                af[mi] = *(const short8v*)&As[(wr * 64 + mi * 16 + fc) * LDT + ks + fk8];
            #pragma unroll
            for (int ni = 0; ni < 4; ++ni)
                bfr[ni] = *(const short8v*)&Bs[(wc * 64 + ni * 16 + fc) * LDT + ks + fk8];
            #pragma unroll
            for (int mi = 0; mi < 4; ++mi)
                #pragma unroll
                for (int ni = 0; ni < 4; ++ni)
                    accv[mi][ni] = __builtin_amdgcn_mfma_f32_16x16x32_bf16(
                        af[mi], bfr[ni], accv[mi][ni], 0, 0, 0);
        }
        __syncthreads();
    }

    // ---- epilogue: C/D layout col=lane&15, row=(lane>>4)*4+j ----
    const int crow0 = bm + wr * 64 + (g << 2);
    const int ccol0 = bn + wc * 64 + fc;
    #pragma unroll
    for (int ni = 0; ni < 4; ++ni) {
        const int col = ccol0 + ni * 16;
        if (col < N) {
            const float bsv = hasBias ? ldf(bias, boff + col, bf) : 0.f;
            #pragma unroll
            for (int mi = 0; mi < 4; ++mi) {
                #pragma unroll
                for (int j = 0; j < 4; ++j) {
                    const int row = crow0 + mi * 16 + j;
                    float r = accv[mi][ni][j] + bsv;
                    if (act == 1) r = softplus_f(r);
                    if (cDt) {
                        ((bf16*)C)[(size_t)row * ldc + col] = __float2bfloat16(r);
                    } else {
                        float* cp = (float*)C + (size_t)row * ldc + col;
                        if (acc) r += *cp;
                        *cp = r;
                    }
                }
            }
        }
    }
}

// ---------------------------------------------------------------------------
// 64x64 MFMA GEMM (N=1024 and N=96 call sites): tile 64x64, TK=64.
// ---------------------------------------------------------------------------
__global__ __launch_bounds__(256) void gemm_k(
    const void* __restrict__ A, int lda, int aDt,
    const void* __restrict__ W, long woff,
    const void* __restrict__ bias, long boff, int hasBias,
    void* __restrict__ C, int ldc, int cDt,
    int N, int K, int act, int acc,
    const int* __restrict__ flagp)
{
    const int bf = *flagp;
    __shared__ short As[BM * LDT];
    __shared__ short Bs[BN * LDT];
    const int bm = blockIdx.y * BM;
    const int bn = blockIdx.x * BN;
    const int tid = threadIdx.x;
    const int lane = tid & 63;
    const int wid = tid >> 6;
    const int wr = wid >> 1, wc = wid & 1;

    const int sa_row = tid >> 2;            // 0..63
    const int sa_kq  = (tid & 3) << 4;      // 0,16,32,48
    const int sb_col = tid & 63;            // 0..63 (wave-coalesced in n)
    const int sb_kq  = (tid >> 6) << 4;     // 0,16,32,48
    const int sb_gn  = bn + sb_col;

    float4v accv[2][2] = {};

    for (int k0 = 0; k0 < K; k0 += TK) {
        {   // A tile
            short8v a0, a1;
            const size_t aoff = (size_t)(bm + sa_row) * lda + k0 + sa_kq;
            if (aDt) {
                a0 = *(const short8v*)((const unsigned short*)A + aoff);
                a1 = *(const short8v*)((const unsigned short*)A + aoff + 8);
            } else {
                const float* ap = (const float*)A + aoff;
                const float4 v0 = *(const float4*)(ap + 0);
                const float4 v1 = *(const float4*)(ap + 4);
                const float4 v2 = *(const float4*)(ap + 8);
                const float4 v3 = *(const float4*)(ap + 12);
                a0[0]=f2bfbits(v0.x); a0[1]=f2bfbits(v0.y); a0[2]=f2bfbits(v0.z); a0[3]=f2bfbits(v0.w);
                a0[4]=f2bfbits(v1.x); a0[5]=f2bfbits(v1.y); a0[6]=f2bfbits(v1.z); a0[7]=f2bfbits(v1.w);
                a1[0]=f2bfbits(v2.x); a1[1]=f2bfbits(v2.y); a1[2]=f2bfbits(v2.z); a1[3]=f2bfbits(v2.w);
                a1[4]=f2bfbits(v3.x); a1[5]=f2bfbits(v3.y); a1[6]=f2bfbits(v3.z); a1[7]=f2bfbits(v3.w);
            }
            *(short8v*)&As[sa_row * LDT + sa_kq + 0] = a0;
            *(short8v*)&As[sa_row * LDT + sa_kq + 8] = a1;
        }
        {   // B tile transposed
            short8v b0, b1;
            #pragma unroll
            for (int j = 0; j < 8; ++j) { b0[j] = 0; b1[j] = 0; }
            if (sb_gn < N) {
                const long wbase = woff + (long)(k0 + sb_kq) * N + sb_gn;
                if (bf) {
                    const unsigned short* wp = (const unsigned short*)W;
                    #pragma unroll
                    for (int j = 0; j < 8; ++j) {
                        b0[j] = (short)wp[wbase + (long)j * N];
                        b1[j] = (short)wp[wbase + (long)(j + 8) * N];
                    }
                } else {
                    const float* wp = (const float*)W;
                    #pragma unroll
                    for (int j = 0; j < 8; ++j) {
                        b0[j] = (short)f2bfbits(wp[wbase + (long)j * N]);
                        b1[j] = (short)f2bfbits(wp[wbase + (long)(j + 8) * N]);
                    }
                }
            }
            *(short8v*)&Bs[sb_col * LDT + sb_kq + 0] = b0;
            *(short8v*)&Bs[sb_col * LDT + sb_kq + 8] = b1;
        }
        __syncthreads();
        {
            const int r  = lane & 15;
            const int kb = (lane >> 4) << 3;   // 0,8,16,24
            #pragma unroll
            for (int ks = 0; ks < TK; ks += 32) {
                const int kg = ks + kb;
                const short8v a0 = *(const short8v*)&As[(wr*32 +      r) * LDT + kg];
                const short8v a1 = *(const short8v*)&As[(wr*32 + 16 + r) * LDT + kg];
                const short8v b0 = *(const short8v*)&Bs[(wc*32 +      r) * LDT + kg];
                const short8v b1 = *(const short8v*)&Bs[(wc*32 + 16 + r) * LDT + kg];
                accv[0][0] = __builtin_amdgcn_mfma_f32_16x16x32_bf16(a0, b0, accv[0][0], 0, 0, 0);
                accv[0][1] = __builtin_amdgcn_mfma_f32_16x16x32_bf16(a0, b1, accv[0][1], 0, 0, 0);
                accv[1][0] = __builtin_amdgcn_mfma_f32_16x16x32_bf16(a1, b0, accv[1][0], 0, 0, 0);
                accv[1][1] = __builtin_amdgcn_mfma_f32_16x16x32_bf16(a1, b1, accv[1][1], 0, 0, 0);
            }
        }
        __syncthreads();
    }

    const int crow0 = bm + wr * 32 + ((lane >> 4) << 2);
    const int ccol0 = bn + wc * 32 + (lane & 15);
    #pragma unroll
    for (int ni = 0; ni < 2; ++ni) {
        const int col = ccol0 + ni * 16;
        if (col < N) {
            const float bsv = hasBias ? ldf(bias, boff + col, bf) : 0.f;
            #pragma unroll
            for (int mi = 0; mi < 2; ++mi) {
                #pragma unroll
                for (int j = 0; j < 4; ++j) {
                    const int row = crow0 + mi * 16 + j;
                    float r = accv[mi][ni][j] + bsv;
                    if (act == 1) r = softplus_f(r);
                    if (cDt) {
                        ((bf16*)C)[(size_t)row * ldc + col] = __float2bfloat16(r);
                    } else {
                        float* cp = (float*)C + (size_t)row * ldc + col;
                        if (acc) r += *cp;
                        *cp = r;
                    }
                }
            }
        }
    }
}

// ---------------------------------------------------------------------------
__global__ __launch_bounds__(256) void cast3_k(const void* __restrict__ x,
    float* __restrict__ a, float* __restrict__ b, float* __restrict__ c,
    const int* __restrict__ flagp)
{
    const int bf = *flagp;
    const int idx = blockIdx.x * 256 + threadIdx.x;
    const float v = ldf(x, idx, bf);
    a[idx] = v; b[idx] = v; c[idx] = v;
}

// ---------------------------------------------------------------------------
__global__ __launch_bounds__(256) void rmsnorm_k(const float* __restrict__ x,
    const void* __restrict__ wgt, long woff, float* __restrict__ out,
    const int* __restrict__ flagp)
{
    const int bf = *flagp;
    const int row = blockIdx.x;
    const float* xr = x + (size_t)row * D_;
    float ss = 0.f;
    for (int i = threadIdx.x; i < D_; i += 256) { const float v = xr[i]; ss = fmaf(v, v, ss); }
    #pragma unroll
    for (int msk = 1; msk < 64; msk <<= 1) ss += __shfl_xor(ss, msk);
    __shared__ float red[4];
    if ((threadIdx.x & 63) == 0) red[threadIdx.x >> 6] = ss;
    __syncthreads();
    ss = red[0] + red[1] + red[2] + red[3];
    const float scale = rsqrtf(ss * (1.f / D_) + 1e-6f);
    float* orow = out + (size_t)row * D_;
    for (int i = threadIdx.x; i < D_; i += 256)
        orow[i] = xr[i] * scale * ldf(wgt, woff + i, bf);
}

// ---------------------------------------------------------------------------
// Depthwise causal conv (K=4) + SiLU. xc = cols [0,DI) of xz16 (stride 2*DI).
// ---------------------------------------------------------------------------
__global__ __launch_bounds__(256) void conv_silu_k(const bf16* __restrict__ xz,
    const void* __restrict__ cw, long cwoff, const void* __restrict__ cb, long cboff,
    bf16* __restrict__ out, const int* __restrict__ flagp)
{
    const int bf = *flagp;
    const int idx = blockIdx.x * 256 + threadIdx.x;
    const int c = idx & (DI_ - 1);
    const int l = (idx >> 11) & (L_ - 1);
    const int b = idx >> 21;
    float acc = ldf(cb, cboff + c, bf);
    #pragma unroll
    for (int j = 0; j < KC_; ++j) {
        const int ls = l - (KC_ - 1) + j;
        if (ls >= 0)
            acc = fmaf(b2f(xz[((size_t)(b * L_ + ls)) * (2 * DI_) + c]),
                       ldf(cw, cwoff + j * DI_ + c, bf), acc);
    }
    out[idx] = __float2bfloat16(silu_f(acc));
}

// ---------------------------------------------------------------------------
// Mamba selective scan — chunk-parallel + XCD swizzle (see round 5 notes).
// ---------------------------------------------------------------------------
#define MS_NCH 16
#define MS_CH  (L_ / MS_NCH)   // 64

__global__ __launch_bounds__(256) void mamba_scan_k(
    const bf16* __restrict__ u, const bf16* __restrict__ dlt,
    const float* __restrict__ xdbl, bf16* __restrict__ xz,
    const void* __restrict__ Alog, long aoff, const void* __restrict__ Dp, long doff,
    const int* __restrict__ flagp)
{
    const int bf = *flagp;
    const int bid = ((blockIdx.x & 7) << 9) | (blockIdx.x >> 3);  // XCD swizzle, B*DI = 4096
    const int d = bid & (DI_ - 1);
    const int b = bid >> 11;
    const int s = threadIdx.x & (DS_ - 1);
    const int c = threadIdx.x >> 4;        // chunk 0..15
    const float Av = -__expf(ldf(Alog, aoff + d * DS_ + s, bf));
    const float Dv = ldf(Dp, doff + d, bf);

    __shared__ float Pl[MS_NCH][DS_];
    __shared__ float Sl[MS_NCH][DS_];

    const int l0 = c * MS_CH;

    // pass 1: chunk-local (P, S)
    float P = 1.f, S = 0.f;
    for (int i = 0; i < MS_CH; ++i) {
        const size_t row = (size_t)(b * L_ + l0 + i);
        const float ut = b2f(u[row * DI_ + d]);
        const float dt = b2f(dlt[row * DI_ + d]);
        const float Bv = xdbl[row * 96 + 64 + s];
        const float dA = __expf(dt * Av);
        P *= dA;
        S = fmaf(S, dA, dt * ut * Bv);
    }
    Pl[c][s] = P; Sl[c][s] = S;
    __syncthreads();

    // prefix combine: h at this chunk's start
    float hs = 0.f;
    for (int cc = 0; cc < c; ++cc) hs = fmaf(hs, Pl[cc][s], Sl[cc][s]);

    // pass 2: rescan with true h0, reduce over s, write y
    for (int i = 0; i < MS_CH; ++i) {
        const size_t row = (size_t)(b * L_ + l0 + i);
        const float ut = b2f(u[row * DI_ + d]);
        const float dt = b2f(dlt[row * DI_ + d]);
        const float Bv = xdbl[row * 96 + 64 + s];
        const float Cv = xdbl[row * 96 + 80 + s];
        const float dA = __expf(dt * Av);
        hs = fmaf(hs, dA, dt * ut * Bv);
        float yp = hs * Cv;
        yp += __shfl_xor(yp, 1, 16);
        yp += __shfl_xor(yp, 2, 16);
        yp += __shfl_xor(yp, 4, 16);
        yp += __shfl_xor(yp, 8, 16);
        if (s == 0) {
            const float z = b2f(xz[row * (2 * DI_) + DI_ + d]);
            xz[row * (2 * DI_) + d] = __float2bfloat16((yp + Dv * ut) * silu_f(z));
        }
    }
}

// ---------------------------------------------------------------------------
__global__ __launch_bounds__(256) void rwkv_mix_k(const float* __restrict__ xn,
    const void* __restrict__ mu, long muoff, bf16* __restrict__ o0,
    bf16* __restrict__ o1, bf16* __restrict__ o2, const int* __restrict__ flagp)
{
    const int bf = *flagp;
    const int idx = blockIdx.x * 256 + threadIdx.x;
    const int d = idx & (D_ - 1);
    const int l = (idx >> 10) & (L_ - 1);
    const float cur = xn[idx];
    const float prev = (l > 0) ? xn[idx - D_] : 0.f;
    const float m0 = ldf(mu, muoff + d, bf);
    const float m1 = ldf(mu, muoff + D_ + d, bf);
    const float m2 = ldf(mu, muoff + 2 * D_ + d, bf);
    o0[idx] = __float2bfloat16(cur * m0 + prev * (1.f - m0));
    o1[idx] = __float2bfloat16(cur * m1 + prev * (1.f - m1));
    o2[idx] = __float2bfloat16(cur * m2 + prev * (1.f - m2));
}

// ---------------------------------------------------------------------------
// RWKV scan — chunk-parallel + XCD swizzle (see round 5 notes).
// ---------------------------------------------------------------------------
#define RW_NCH 16
#define RW_CH  (L_ / RW_NCH)   // 64

__global__ __launch_bounds__(1024) void rwkv_scan_k(const bf16* __restrict__ R,
    const bf16* __restrict__ Kb, const bf16* __restrict__ V,
    const void* __restrict__ wlog, long woff, const void* __restrict__ uu, long uoff,
    bf16* __restrict__ Y, const int* __restrict__ flagp)
{
    const int bf = *flagp;
    const int bid = ((blockIdx.x & 7) << 8) | (blockIdx.x >> 3);  // XCD swizzle, B*HR*DHR = 2048
    const int v = bid & (DHR_ - 1);
    const int h = (bid >> 6) & (HR_ - 1);
    const int b = bid >> 10;
    const int k = threadIdx.x & 63;
    const int c = threadIdx.x >> 6;       // chunk 0..15
    const float ew = __expf(ldf(wlog, woff + h * DHR_ + k, bf));
    const float w  = __expf(-ew);
    const float wC = __expf(-ew * (float)RW_CH);   // w^CH
    const float uv = ldf(uu, uoff + h * DHR_ + k, bf);

    __shared__ float Se[RW_NCH][64];

    const int l0 = c * RW_CH;

    // pass 1: chunk-local S_end (S0 = 0)
    float S = 0.f;
    for (int i = 0; i < RW_CH; ++i) {
        const size_t off = ((size_t)(b * L_ + l0 + i)) * D_ + h * DHR_;
        const float kk = b2f(Kb[off + k]);
        const float vt = b2f(V[off + v]);
        S = fmaf(w, S, kk * vt);
    }
    Se[c][k] = S;
    __syncthreads();

    // prefix: S at this chunk's start
    S = 0.f;
    for (int cc = 0; cc < c; ++cc) S = fmaf(wC, S, Se[cc][k]);

    // pass 2: rescan with true S0, reduce over k, write y
    for (int i = 0; i < RW_CH; ++i) {
        const size_t off = ((size_t)(b * L_ + l0 + i)) * D_ + h * DHR_;
        const float r  = b2f(R[off + k]);
        const float kk = b2f(Kb[off + k]);
        const float vt = b2f(V[off + v]);
        const float kv = kk * vt;
        float yp = r * fmaf(uv, kv, S);
        S = fmaf(w, S, kv);
        yp += __shfl_xor(yp, 1);
        yp += __shfl_xor(yp, 2);
        yp += __shfl_xor(yp, 4);
        yp += __shfl_xor(yp, 8);
        yp += __shfl_xor(yp, 16);
        yp += __shfl_xor(yp, 32);
        if (k == 0) Y[off + v] = __float2bfloat16(yp);
    }
}

// ---------------------------------------------------------------------------
// MHA flash attention — MFMA version (see round 4 notes).
// ---------------------------------------------------------------------------
#define LDK 40   // Ks row pitch (bf16): 80B, 16B-aligned, 2-way banks (free)
#define LDV 72   // Vt/Ps row pitch (bf16): 144B, 16B-aligned, 2-way banks

__global__ __launch_bounds__(256) void mha_attn_k(const bf16* __restrict__ Q,
    const bf16* __restrict__ Kx, const bf16* __restrict__ V, bf16* __restrict__ O)
{
    const int b = blockIdx.z, h = blockIdx.y;
    const int qt = blockIdx.x;            // 0..15
    const int tid = threadIdx.x;
    const int lane = tid & 63;
    const int wid = tid >> 6;

    __shared__ __align__(16) short Ks[64 * LDK];
    __shared__ __align__(16) short Vt[32 * LDV];
    __shared__ __align__(16) short Ps[4][16 * LDV];

    const int fc  = lane & 15;            // A-row / B-col within fragment
    const int g   = lane >> 4;            // k-octet group; C rows = g*4+j
    const int fk8 = g << 3;               // 0,8,16,24

    const int q0 = qt * 64 + wid * 16;

    // Q fragment (K=32 = full head dim), loaded once
    const size_t qoff = ((size_t)(b * L_ + q0 + fc)) * D_ + h * DHA_ + fk8;
    const short8v qf = *(const short8v*)((const unsigned short*)Q + qoff);

    float4v o0 = {}, o1 = {};
    float m[4] = {-1e30f, -1e30f, -1e30f, -1e30f};
    float l[4] = {0.f, 0.f, 0.f, 0.f};
    const float scale = 0.1767766952966369f;   // 1/sqrt(32)

    // staging indices: thread t covers (row=t>>2, d-octet=(t&3)*8)
    const int sr = tid >> 2;
    const int sc = (tid & 3) << 3;

    for (int kt = 0; kt < L_; kt += 64) {
        __syncthreads();   // all waves done reading previous Ks/Vt
        {
            const size_t koff = ((size_t)(b * L_ + kt + sr)) * D_ + h * DHA_ + sc;
            const short8v k8 = *(const short8v*)((const unsigned short*)Kx + koff);
            *(short8v*)&Ks[sr * LDK + sc] = k8;
            const short8v v8 = *(const short8v*)((const unsigned short*)V + koff);
            #pragma unroll
            for (int j = 0; j < 8; ++j)
                Vt[(sc + j) * LDV + sr] = v8[j];
        }
        __syncthreads();

        // ---- QK^T: 4 mfma over 4 kv-16 sub-tiles ----
        float4v sv[4];
        #pragma unroll
        for (int nt = 0; nt < 4; ++nt) {
            const short8v kf = *(const short8v*)&Ks[(nt * 16 + fc) * LDK + fk8];
            float4v z = {};
            sv[nt] = __builtin_amdgcn_mfma_f32_16x16x32_bf16(qf, kf, z, 0, 0, 0);
        }

        // ---- online softmax (rows g*4+j, cols nt*16+fc) ----
        #pragma unroll
        for (int j = 0; j < 4; ++j) {
            float mt = fmaxf(fmaxf(sv[0][j], sv[1][j]), fmaxf(sv[2][j], sv[3][j])) * scale;
            #pragma unroll
            for (int msk = 1; msk < 16; msk <<= 1) mt = fmaxf(mt, __shfl_xor(mt, msk));
            const float mn = fmaxf(m[j], mt);
            const float corr = __expf(m[j] - mn);
            m[j] = mn;
            float sum = 0.f;
            #pragma unroll
            for (int nt = 0; nt < 4; ++nt) {
                const float p = __expf(fmaf(sv[nt][j], scale, -mn));
                sum += p;
                Ps[wid][(g * 4 + j) * LDV + nt * 16 + fc] = (short)f2bfbits(p);
            }
            #pragma unroll
            for (int msk = 1; msk < 16; msk <<= 1) sum += __shfl_xor(sum, msk);
            l[j] = l[j] * corr + sum;
            o0[j] *= corr;
            o1[j] *= corr;
        }

        // ---- PV: O += P(16x64) . V(64x32), 2 k-chunks x 2 d-tiles ----
        #pragma unroll
        for (int kc = 0; kc < 2; ++kc) {
            const short8v pf = *(const short8v*)&Ps[wid][fc * LDV + kc * 32 + fk8];
            const short8v v0 = *(const short8v*)&Vt[(fc) * LDV + kc * 32 + fk8];
            const short8v v1 = *(const short8v*)&Vt[(16 + fc) * LDV + kc * 32 + fk8];
            o0 = __builtin_amdgcn_mfma_f32_16x16x32_bf16(pf, v0, o0, 0, 0, 0);
            o1 = __builtin_amdgcn_mfma_f32_16x16x32_bf16(pf, v1, o1, 0, 0, 0);
        }
    }

    // ---- epilogue ----
    #pragma unroll
    for (int j = 0; j < 4; ++j) {
        const float inv = 1.f / l[j];
        const size_t ooff = ((size_t)(b * L_ + q0 + g * 4 + j)) * D_ + h * DHA_;
        O[ooff + fc]      = __float2bfloat16(o0[j] * inv);
        O[ooff + 16 + fc] = __float2bfloat16(o1[j] * inv);
    }
}

// ---------------------------------------------------------------------------
// Final: logits = [m,r,t] @ f_W + f_b; softmax over 3; fp32 out.
// ---------------------------------------------------------------------------
__global__ __launch_bounds__(256) void final_k(const float* __restrict__ m,
    const float* __restrict__ r, const float* __restrict__ t,
    const void* __restrict__ fW, const void* __restrict__ fb,
    float* __restrict__ out, const int* __restrict__ flagp)
{
    const int bf = *flagp;
    const int row = blockIdx.x;
    float p0 = 0.f, p1 = 0.f, p2 = 0.f;
    for (int i = threadIdx.x; i < 3 * D_; i += 256) {
        float v;
        if (i < D_)          v = m[(size_t)row * D_ + i];
        else if (i < 2 * D_) v = r[(size_t)row * D_ + i - D_];
        else                 v = t[(size_t)row * D_ + i - 2 * D_];
        p0 = fmaf(v, ldf(fW, (long)i * 3 + 0, bf), p0);
        p1 = fmaf(v, ldf(fW, (long)i * 3 + 1, bf), p1);
        p2 = fmaf(v, ldf(fW, (long)i * 3 + 2, bf), p2);
    }
    #pragma unroll
    for (int msk = 1; msk < 64; msk <<= 1) {
        p0 += __shfl_xor(p0, msk);
        p1 += __shfl_xor(p1, msk);
        p2 += __shfl_xor(p2, msk);
    }
    __shared__ float red[4][3];
    if ((threadIdx.x & 63) == 0) {
        const int w = threadIdx.x >> 6;
        red[w][0] = p0; red[w][1] = p1; red[w][2] = p2;
    }
    __syncthreads();
    if (threadIdx.x == 0) {
        const float l0 = red[0][0] + red[1][0] + red[2][0] + red[3][0] + ldf(fb, 0, bf);
        const float l1 = red[0][1] + red[1][1] + red[2][1] + red[3][1] + ldf(fb, 1, bf);
        const float l2 = red[0][2] + red[1][2] + red[2][2] + red[3][2] + ldf(fb, 2, bf);
        const float mx = fmaxf(l0, fmaxf(l1, l2));
        const float e0 = __expf(l0 - mx), e1 = __expf(l1 - mx), e2 = __expf(l2 - mx);
        const float inv = 1.f / (e0 + e1 + e2);
        out[row * 3 + 0] = e0 * inv;
        out[row * 3 + 1] = e1 * inv;
        out[row * 3 + 2] = e2 * inv;
    }
}

// ---------------------------------------------------------------------------
extern "C" void kernel_launch(void* const* d_in, const int* in_sizes, int n_in,
                              void* d_out, int out_size, void* d_ws, size_t ws_size,
                              hipStream_t stream)
{
    float* out = (float*)d_out;

    // ---- self-diagnosis: verify input sizes (dict order) -------------------
    static const int expected[29] = {
        2097152, 6144, 25165824, 49152, 12288, 1179648, 786432, 12288,
        196608, 12288, 12582912, 4096, 12288, 4194304, 4194304, 4194304,
        4194304, 4096, 4096, 2097152, 2048, 2097152, 2048, 2097152, 2048,
        2097152, 2048, 9216, 3 };
    int bad = (n_in == 29) ? -1 : 29;
    if (bad < 0)
        for (int i = 0; i < 29; ++i)
            if (in_sizes[i] != expected[i]) { bad = i; break; }
    if (bad >= 0) {
        diag_k<<<24, 256, 0, stream>>>(out, 1000.f + 8.f * bad);
        return;
    }

    // ---- workspace layout (56.8 MB total) ----------------------------------
    const size_t REQ = 64 + 3ull * 8388608 + 8388608 + 16777216 + 8388608 + 786432;
    if (ws_size < REQ) {
        diag_k<<<24, 256, 0, stream>>>(out, 2048.f + (float)(ws_size >> 20));
        return;
    }
    char* base = (char*)d_ws;
    int*   flag = (int*)base;
    float* resM = (float*)(base + 64);
    float* resR = resM + 2097152;
    float* resT = resR + 2097152;
    float* bufN = resT + 2097152;                 // fp32 xn (NBL*D) / bf16 delta (NBL*DI)
    bf16*  XZ16 = (bf16*)(bufN + 2097152);        // NBL*4096
    bf16*  U16  = XZ16 + (size_t)NBL * 4096;      // NBL*2048
    float* XD   = (float*)(U16 + (size_t)NBL * 2048); // NBL*96

    // quarter views of XZ16 (NBL*1024 each, contiguous)
    bf16* q0 = XZ16;
    bf16* q1 = XZ16 + 1 * 2097152;
    bf16* q2 = XZ16 + 2 * 2097152;
    bf16* q3 = XZ16 + 3 * 2097152;
    bf16* u0 = U16;
    bf16* u1 = U16 + 2097152;

    const void* x        = d_in[0];
    const void* m_norm   = d_in[1];
    const void* m_Win    = d_in[2];
    const void* m_conv_w = d_in[3];
    const void* m_conv_b = d_in[4];
    const void* m_Wx     = d_in[5];
    const void* m_Wdt    = d_in[6];
    const void* m_bdt    = d_in[7];
    const void* m_Alog   = d_in[8];
    const void* m_D      = d_in[9];
    const void* m_Wout   = d_in[10];
    const void* r_norm   = d_in[11];
    const void* r_mu     = d_in[12];
    const void* r_Wr     = d_in[13];
    const void* r_Wk     = d_in[14];
    const void* r_Wv     = d_in[15];
    const void* r_Wo     = d_in[16];
    const void* r_wlog   = d_in[17];
    const void* r_u      = d_in[18];
    const void* a_Wq     = d_in[19];
    const void* a_bq     = d_in[20];
    const void* a_Wk     = d_in[21];
    const void* a_bk     = d_in[22];
    const void* a_Wv     = d_in[23];
    const void* a_bv     = d_in[24];
    const void* a_Wo     = d_in[25];
    const void* a_bo     = d_in[26];
    const void* f_W      = d_in[27];
    const void* f_b      = d_in[28];

    auto gemm = [&](const void* A, int lda, int aDt, const void* W, long woff,
                    const void* bias, long boff, int hasBias,
                    void* C, int ldc, int cDt, int N, int K, int act, int acc) {
        if ((N & 127) == 0 && N >= 2048 && (K & 63) == 0) {
            dim3 g(N / 128, NBL / 128);
            gemm_big_k<<<g, 256, 0, stream>>>(A, lda, aDt, W, woff, bias, boff,
                hasBias, C, ldc, cDt, N, K, act, acc, flag);
        } else {
            dim3 g((N + BN - 1) / BN, NBL / BM);
            gemm_k<<<g, 256, 0, stream>>>(A, lda, aDt, W, woff, bias, boff, hasBias,
                                          C, ldc, cDt, N, K, act, acc, flag);
        }
    };

    detect_k<<<1, 64, 0, stream>>>(x, flag);
    cast3_k<<<8192, 256, 0, stream>>>(x, resM, resR, resT, flag);

    // ---------------- Mamba branch ----------------
    for (int i = 0; i < NM_; ++i) {
        rmsnorm_k<<<NBL, 256, 0, stream>>>(resM, m_norm, (long)i * D_, bufN, flag);
        gemm(bufN, D_, 0, m_Win, (long)i * D_ * 2 * DI_, nullptr, 0, 0,
             XZ16, 2 * DI_, 1, 2 * DI_, D_, 0, 0);
        conv_silu_k<<<16384, 256, 0, stream>>>(XZ16, m_conv_w, (long)i * KC_ * DI_,
                                               m_conv_b, (long)i * DI_, U16, flag);
        gemm(U16, DI_, 1, m_Wx, (long)i * DI_ * 96, nullptr, 0, 0,
             XD, 96, 0, 96, DI_, 0, 0);
        gemm(XD, 96, 0, m_Wdt, (long)i * DTR_ * DI_, m_bdt, (long)i * DI_, 1,
             bufN, DI_, 1, DI_, DTR_, 1 /*softplus*/, 0);
        mamba_scan_k<<<B_ * DI_, 256, 0, stream>>>(U16, (const bf16*)bufN, XD, XZ16,
            m_Alog, (long)i * DI_ * DS_, m_D, (long)i * DI_, flag);
        gemm(XZ16, 2 * DI_, 1, m_Wout, (long)i * DI_ * D_, nullptr, 0, 0,
             resM, D_, 0, D_, DI_, 0, 1 /*acc*/);
    }

    // ---------------- RWKV branch ----------------
    for (int i = 0; i < NR_; ++i) {
        rmsnorm_k<<<NBL, 256, 0, stream>>>(resR, r_norm, (long)i * D_, bufN, flag);
        rwkv_mix_k<<<8192, 256, 0, stream>>>(bufN, r_mu, (long)i * 3 * D_,
                                             q0, q1, q2, flag);
        gemm(q0, D_, 1, r_Wr, (long)i * D_ * D_, nullptr, 0, 0, u0, D_, 1, D_, D_, 0, 0);
        gemm(q1, D_, 1, r_Wk, (long)i * D_ * D_, nullptr, 0, 0, u1, D_, 1, D_, D_, 0, 0);
        gemm(q2, D_, 1, r_Wv, (long)i * D_ * D_, nullptr, 0, 0, q3, D_, 1, D_, D_, 0, 0);
        rwkv_scan_k<<<B_ * HR_ * DHR_, RW_NCH * 64, 0, stream>>>(u0, u1, q3,
            r_wlog, (long)i * HR_ * DHR_, r_u, (long)i * HR_ * DHR_, q0, flag);
        gemm(q0, D_, 1, r_Wo, (long)i * D_ * D_, nullptr, 0, 0, resR, D_, 0, D_, D_, 0, 1);
    }

    // ---------------- MHA branch (no norm, no residual) ----------------
    for (int i = 0; i < NT_; ++i) {
        gemm(resT, D_, 0, a_Wq, (long)i * D_ * HA_ * DHA_, a_bq, (long)i * HA_ * DHA_, 1,
             u0, D_, 1, D_, D_, 0, 0);
        gemm(resT, D_, 0, a_Wk, (long)i * D_ * HA_ * DHA_, a_bk, (long)i * HA_ * DHA_, 1,
             u1, D_, 1, D_, D_, 0, 0);
        gemm(resT, D_, 0, a_Wv, (long)i * D_ * HA_ * DHA_, a_bv, (long)i * HA_ * DHA_, 1,
             q3, D_, 1, D_, D_, 0, 0);
        mha_attn_k<<<dim3(L_ / 64, HA_, B_), 256, 0, stream>>>(u0, u1, q3, q0);
        gemm(q0, D_, 1, a_Wo, (long)i * HA_ * DHA_ * D_, a_bo, (long)i * D_, 1,
             resT, D_, 0, D_, HA_ * DHA_, 0, 0 /*no residual*/);
    }

    // ---------------- combine + softmax ----------------
    final_k<<<NBL, 256, 0, stream>>>(resM, resR, resT, f_W, f_b, out, flag);
}

// Round 8
// 3997.650 us; speedup vs baseline: 1.0687x; 1.0220x over previous
//
#include <hip/hip_runtime.h>
#include <hip/hip_bf16.h>
#include <cstddef>

#define D_   1024
#define DI_  2048
#define DS_  16
#define DTR_ 64
#define KC_  4
#define HR_  16
#define DHR_ 64
#define HA_  32
#define DHA_ 32
#define NM_  6
#define NR_  4
#define NT_  2
#define B_   2
#define L_   1024
#define NBL  (B_*L_)   // 2048 rows

typedef __hip_bfloat16 bf16;
typedef __attribute__((ext_vector_type(8))) short short8v;   // 8 bf16 (4 VGPRs)
typedef __attribute__((ext_vector_type(4))) float float4v;   // MFMA C/D frag

__device__ __forceinline__ float bfbits2f(unsigned short u) {
    return __uint_as_float(((unsigned int)u) << 16);
}
__device__ __forceinline__ float b2f(bf16 x) { return __bfloat162float(x); }
__device__ __forceinline__ unsigned short f2bfbits(float f) {
    bf16 h = __float2bfloat16(f);
    return *reinterpret_cast<unsigned short*>(&h);
}
// dtype-dispatched model-input load: bf==1 -> bf16, bf==0 -> fp32
__device__ __forceinline__ float ldf(const void* p, long i, int bf) {
    if (bf) return bfbits2f(((const unsigned short*)p)[i]);
    return ((const float*)p)[i];
}
__device__ __forceinline__ float softplus_f(float x) {
    return x > 20.f ? x : log1pf(__expf(x));
}
__device__ __forceinline__ float silu_f(float x) {
    return x / (1.f + __expf(-x));
}

// ---------------------------------------------------------------------------
// Diagnostic writer (fp32 out): zeros the output, writes a code into out[0].
// ---------------------------------------------------------------------------
__global__ __launch_bounds__(256) void diag_k(float* __restrict__ out, float code)
{
    const int idx = blockIdx.x * 256 + threadIdx.x;
    if (idx < NBL * 3) out[idx] = (idx == 0 ? code : 0.f);
}

// ---------------------------------------------------------------------------
// Input dtype detection (1 wave).
// ---------------------------------------------------------------------------
__global__ __launch_bounds__(64) void detect_k(const void* __restrict__ x,
                                               int* __restrict__ flag)
{
    const unsigned short* u = (const unsigned short*)x;
    int local = 0;
    for (int i = threadIdx.x; i < 1024; i += 64) {
        const float av = fabsf(bfbits2f(u[i]));
        if (!(av < 1e6f)) local = 1;   // catches huge and NaN
    }
    const unsigned long long b = __ballot(local);
    if (threadIdx.x == 0) flag[0] = b ? 0 : 1;  // 1 => inputs are bf16
}

// ---------------------------------------------------------------------------
// Weight pre-convert: W [K][N] (model dtype) -> WT bf16 [N][K] (transposed).
// LDS 32x33 tile; both global sides coalesced.  N%32==0, K%32==0 required.
// The gemm B-stage then mirrors the cheap bf16 A-stage (contiguous short8v
// loads, zero cvt VALU) instead of 32 strided dword loads + cvt per thread.
// ---------------------------------------------------------------------------
__global__ __launch_bounds__(256) void wcvt_k(const void* __restrict__ W, long woff,
    int N, int K, bf16* __restrict__ WT, const int* __restrict__ flagp)
{
    const int bf = *flagp;
    __shared__ float t[32][33];
    const int nt = blockIdx.x << 5;
    const int kt = blockIdx.y << 5;
    const int tx = threadIdx.x & 31;
    const int ty = threadIdx.x >> 5;   // 0..7
    #pragma unroll
    for (int i = 0; i < 4; ++i) {
        const int k = ty + i * 8;
        t[k][tx] = ldf(W, woff + (long)(kt + k) * N + nt + tx, bf);
    }
    __syncthreads();
    #pragma unroll
    for (int i = 0; i < 4; ++i) {
        const int n = ty + i * 8;
        WT[(size_t)(nt + n) * K + kt + tx] = __float2bfloat16(t[tx][n]);
    }
}

#define BM 64
#define BN 64
#define TK 64
#define LDT 72

// ---------------------------------------------------------------------------
// Big MFMA GEMM: 128x128 tile, for N >= 2048 (grid >= 256... Win 512 blocks).
// wDt=1: W is pre-converted bf16 WT [N][K]; B-stage = vectorized short8 copy.
// wDt=0: legacy raw W [K][N] model-dtype strided path (Wdt only).
// ---------------------------------------------------------------------------
__global__ __launch_bounds__(256) void gemm_big_k(
    const void* __restrict__ A, int lda, int aDt,
    const void* __restrict__ W, long woff, int wDt,
    const void* __restrict__ bias, long boff, int hasBias,
    void* __restrict__ C, int ldc, int cDt,
    int N, int K, int act, int acc,
    const int* __restrict__ flagp)
{
    const int bf = *flagp;
    __shared__ short As[128 * LDT];
    __shared__ short Bs[128 * LDT];
    const int bm = blockIdx.y * 128;
    const int bn = blockIdx.x * 128;
    const int tid = threadIdx.x;
    const int lane = tid & 63;
    const int wid = tid >> 6;
    const int wr = wid >> 1, wc = wid & 1;

    const int fc  = lane & 15;
    const int g   = lane >> 4;
    const int fk8 = g << 3;

    const int sa_row = tid >> 1;          // 0..127
    const int sa_k   = (tid & 1) << 5;    // 0 / 32

    float4v accv[4][4] = {};

    for (int k0 = 0; k0 < K; k0 += TK) {
        // ---- stage A tile (128 rows x 64 k), 32 bf16 per thread ----
        if (aDt) {
            const unsigned short* ap = (const unsigned short*)A
                + (size_t)(bm + sa_row) * lda + k0 + sa_k;
            #pragma unroll
            for (int q = 0; q < 4; ++q)
                *(short8v*)&As[sa_row * LDT + sa_k + q * 8] =
                    *(const short8v*)(ap + q * 8);
        } else {
            const float* ap = (const float*)A + (size_t)(bm + sa_row) * lda + k0 + sa_k;
            #pragma unroll
            for (int q = 0; q < 4; ++q) {
                const float4 v0 = *(const float4*)(ap + q * 8);
                const float4 v1 = *(const float4*)(ap + q * 8 + 4);
                short8v t;
                t[0]=(short)f2bfbits(v0.x); t[1]=(short)f2bfbits(v0.y);
                t[2]=(short)f2bfbits(v0.z); t[3]=(short)f2bfbits(v0.w);
                t[4]=(short)f2bfbits(v1.x); t[5]=(short)f2bfbits(v1.y);
                t[6]=(short)f2bfbits(v1.z); t[7]=(short)f2bfbits(v1.w);
                *(short8v*)&As[sa_row * LDT + sa_k + q * 8] = t;
            }
        }
        // ---- stage B tile: Bs[n][k] ----
        if (wDt) {
            const unsigned short* wp = (const unsigned short*)W
                + (size_t)(bn + sa_row) * K + k0 + sa_k;
            #pragma unroll
            for (int q = 0; q < 4; ++q)
                *(short8v*)&Bs[sa_row * LDT + sa_k + q * 8] =
                    *(const short8v*)(wp + q * 8);
        } else {
            const int sb_n = tid & 127;
            const int sb_k = (tid >> 7) << 5;
            const long wbase = woff + (long)(k0 + sb_k) * N + (bn + sb_n);
            short tmp[32];
            if (bf) {
                const unsigned short* wp = (const unsigned short*)W;
                #pragma unroll
                for (int j = 0; j < 32; ++j) tmp[j] = (short)wp[wbase + (long)j * N];
            } else {
                const float* wp = (const float*)W;
                #pragma unroll
                for (int j = 0; j < 32; ++j) tmp[j] = (short)f2bfbits(wp[wbase + (long)j * N]);
            }
            #pragma unroll
            for (int q = 0; q < 4; ++q) {
                short8v t;
                #pragma unroll
                for (int e = 0; e < 8; ++e) t[e] = tmp[q * 8 + e];
                *(short8v*)&Bs[sb_n * LDT + sb_k + q * 8] = t;
            }
        }
        __syncthreads();
        // ---- MFMA: 32 per wave per K-tile ----
        #pragma unroll
        for (int ks = 0; ks < TK; ks += 32) {
            short8v af[4], bfr[4];
            #pragma unroll
            for (int mi = 0; mi < 4; ++mi)
                af[mi] = *(const short8v*)&As[(wr * 64 + mi * 16 + fc) * LDT + ks + fk8];
            #pragma unroll
            for (int ni = 0; ni < 4; ++ni)
                bfr[ni] = *(const short8v*)&Bs[(wc * 64 + ni * 16 + fc) * LDT + ks + fk8];
            #pragma unroll
            for (int mi = 0; mi < 4; ++mi)
                #pragma unroll
                for (int ni = 0; ni < 4; ++ni)
                    accv[mi][ni] = __builtin_amdgcn_mfma_f32_16x16x32_bf16(
                        af[mi], bfr[ni], accv[mi][ni], 0, 0, 0);
        }
        __syncthreads();
    }

    // ---- epilogue: C/D layout col=lane&15, row=(lane>>4)*4+j ----
    const int crow0 = bm + wr * 64 + (g << 2);
    const int ccol0 = bn + wc * 64 + fc;
    #pragma unroll
    for (int ni = 0; ni < 4; ++ni) {
        const int col = ccol0 + ni * 16;
        if (col < N) {
            const float bsv = hasBias ? ldf(bias, boff + col, bf) : 0.f;
            #pragma unroll
            for (int mi = 0; mi < 4; ++mi) {
                #pragma unroll
                for (int j = 0; j < 4; ++j) {
                    const int row = crow0 + mi * 16 + j;
                    float r = accv[mi][ni][j] + bsv;
                    if (act == 1) r = softplus_f(r);
                    if (cDt) {
                        ((bf16*)C)[(size_t)row * ldc + col] = __float2bfloat16(r);
                    } else {
                        float* cp = (float*)C + (size_t)row * ldc + col;
                        if (acc) r += *cp;
                        *cp = r;
                    }
                }
            }
        }
    }
}

// ---------------------------------------------------------------------------
// 64x64 MFMA GEMM (N=1024 / N=96): wDt=1 -> WT bf16 [N][K] vector staging.
// ---------------------------------------------------------------------------
__global__ __launch_bounds__(256) void gemm_k(
    const void* __restrict__ A, int lda, int aDt,
    const void* __restrict__ W, long woff, int wDt,
    const void* __restrict__ bias, long boff, int hasBias,
    void* __restrict__ C, int ldc, int cDt,
    int N, int K, int act, int acc,
    const int* __restrict__ flagp)
{
    const int bf = *flagp;
    __shared__ short As[BM * LDT];
    __shared__ short Bs[BN * LDT];
    const int bm = blockIdx.y * BM;
    const int bn = blockIdx.x * BN;
    const int tid = threadIdx.x;
    const int lane = tid & 63;
    const int wid = tid >> 6;
    const int wr = wid >> 1, wc = wid & 1;

    const int sa_row = tid >> 2;            // 0..63
    const int sa_kq  = (tid & 3) << 4;      // 0,16,32,48

    float4v accv[2][2] = {};

    for (int k0 = 0; k0 < K; k0 += TK) {
        {   // A tile
            short8v a0, a1;
            const size_t aoff = (size_t)(bm + sa_row) * lda + k0 + sa_kq;
            if (aDt) {
                a0 = *(const short8v*)((const unsigned short*)A + aoff);
                a1 = *(const short8v*)((const unsigned short*)A + aoff + 8);
            } else {
                const float* ap = (const float*)A + aoff;
                const float4 v0 = *(const float4*)(ap + 0);
                const float4 v1 = *(const float4*)(ap + 4);
                const float4 v2 = *(const float4*)(ap + 8);
                const float4 v3 = *(const float4*)(ap + 12);
                a0[0]=f2bfbits(v0.x); a0[1]=f2bfbits(v0.y); a0[2]=f2bfbits(v0.z); a0[3]=f2bfbits(v0.w);
                a0[4]=f2bfbits(v1.x); a0[5]=f2bfbits(v1.y); a0[6]=f2bfbits(v1.z); a0[7]=f2bfbits(v1.w);
                a1[0]=f2bfbits(v2.x); a1[1]=f2bfbits(v2.y); a1[2]=f2bfbits(v2.z); a1[3]=f2bfbits(v2.w);
                a1[4]=f2bfbits(v3.x); a1[5]=f2bfbits(v3.y); a1[6]=f2bfbits(v3.z); a1[7]=f2bfbits(v3.w);
            }
            *(short8v*)&As[sa_row * LDT + sa_kq + 0] = a0;
            *(short8v*)&As[sa_row * LDT + sa_kq + 8] = a1;
        }
        if (wDt) {   // B tile from WT bf16 [N][K]
            if (bn + sa_row < N) {
                const unsigned short* wp = (const unsigned short*)W
                    + (size_t)(bn + sa_row) * K + k0 + sa_kq;
                *(short8v*)&Bs[sa_row * LDT + sa_kq + 0] = *(const short8v*)(wp);
                *(short8v*)&Bs[sa_row * LDT + sa_kq + 8] = *(const short8v*)(wp + 8);
            } else {
                short8v z;
                #pragma unroll
                for (int e = 0; e < 8; ++e) z[e] = 0;
                *(short8v*)&Bs[sa_row * LDT + sa_kq + 0] = z;
                *(short8v*)&Bs[sa_row * LDT + sa_kq + 8] = z;
            }
        } else {     // legacy raw W [K][N]
            const int sb_col = tid & 63;
            const int sb_kq  = (tid >> 6) << 4;
            const int sb_gn  = bn + sb_col;
            short8v b0, b1;
            #pragma unroll
            for (int j = 0; j < 8; ++j) { b0[j] = 0; b1[j] = 0; }
            if (sb_gn < N) {
                const long wbase = woff + (long)(k0 + sb_kq) * N + sb_gn;
                if (bf) {
                    const unsigned short* wp = (const unsigned short*)W;
                    #pragma unroll
                    for (int j = 0; j < 8; ++j) {
                        b0[j] = (short)wp[wbase + (long)j * N];
                        b1[j] = (short)wp[wbase + (long)(j + 8) * N];
                    }
                } else {
                    const float* wp = (const float*)W;
                    #pragma unroll
                    for (int j = 0; j < 8; ++j) {
                        b0[j] = (short)f2bfbits(wp[wbase + (long)j * N]);
                        b1[j] = (short)f2bfbits(wp[wbase + (long)(j + 8) * N]);
                    }
                }
            }
            *(short8v*)&Bs[sb_col * LDT + sb_kq + 0] = b0;
            *(short8v*)&Bs[sb_col * LDT + sb_kq + 8] = b1;
        }
        __syncthreads();
        {
            const int r  = lane & 15;
            const int kb = (lane >> 4) << 3;   // 0,8,16,24
            #pragma unroll
            for (int ks = 0; ks < TK; ks += 32) {
                const int kg = ks + kb;
                const short8v a0 = *(const short8v*)&As[(wr*32 +      r) * LDT + kg];
                const short8v a1 = *(const short8v*)&As[(wr*32 + 16 + r) * LDT + kg];
                const short8v b0 = *(const short8v*)&Bs[(wc*32 +      r) * LDT + kg];
                const short8v b1 = *(const short8v*)&Bs[(wc*32 + 16 + r) * LDT + kg];
                accv[0][0] = __builtin_amdgcn_mfma_f32_16x16x32_bf16(a0, b0, accv[0][0], 0, 0, 0);
                accv[0][1] = __builtin_amdgcn_mfma_f32_16x16x32_bf16(a0, b1, accv[0][1], 0, 0, 0);
                accv[1][0] = __builtin_amdgcn_mfma_f32_16x16x32_bf16(a1, b0, accv[1][0], 0, 0, 0);
                accv[1][1] = __builtin_amdgcn_mfma_f32_16x16x32_bf16(a1, b1, accv[1][1], 0, 0, 0);
            }
        }
        __syncthreads();
    }

    const int crow0 = bm + wr * 32 + ((lane >> 4) << 2);
    const int ccol0 = bn + wc * 32 + (lane & 15);
    #pragma unroll
    for (int ni = 0; ni < 2; ++ni) {
        const int col = ccol0 + ni * 16;
        if (col < N) {
            const float bsv = hasBias ? ldf(bias, boff + col, bf) : 0.f;
            #pragma unroll
            for (int mi = 0; mi < 2; ++mi) {
                #pragma unroll
                for (int j = 0; j < 4; ++j) {
                    const int row = crow0 + mi * 16 + j;
                    float r = accv[mi][ni][j] + bsv;
                    if (act == 1) r = softplus_f(r);
                    if (cDt) {
                        ((bf16*)C)[(size_t)row * ldc + col] = __float2bfloat16(r);
                    } else {
                        float* cp = (float*)C + (size_t)row * ldc + col;
                        if (acc) r += *cp;
                        *cp = r;
                    }
                }
            }
        }
    }
}

// ---------------------------------------------------------------------------
__global__ __launch_bounds__(256) void cast3_k(const void* __restrict__ x,
    float* __restrict__ a, float* __restrict__ b, float* __restrict__ c,
    const int* __restrict__ flagp)
{
    const int bf = *flagp;
    const int idx = blockIdx.x * 256 + threadIdx.x;
    const float v = ldf(x, idx, bf);
    a[idx] = v; b[idx] = v; c[idx] = v;
}

// ---------------------------------------------------------------------------
// RMSNorm, bf16 output (consumers quantize to bf16 anyway).
// ---------------------------------------------------------------------------
__global__ __launch_bounds__(256) void rmsnorm_k(const float* __restrict__ x,
    const void* __restrict__ wgt, long woff, bf16* __restrict__ out,
    const int* __restrict__ flagp)
{
    const int bf = *flagp;
    const int row = blockIdx.x;
    const float* xr = x + (size_t)row * D_;
    float ss = 0.f;
    for (int i = threadIdx.x; i < D_; i += 256) { const float v = xr[i]; ss = fmaf(v, v, ss); }
    #pragma unroll
    for (int msk = 1; msk < 64; msk <<= 1) ss += __shfl_xor(ss, msk);
    __shared__ float red[4];
    if ((threadIdx.x & 63) == 0) red[threadIdx.x >> 6] = ss;
    __syncthreads();
    ss = red[0] + red[1] + red[2] + red[3];
    const float scale = rsqrtf(ss * (1.f / D_) + 1e-6f);
    bf16* orow = out + (size_t)row * D_;
    for (int i = threadIdx.x; i < D_; i += 256)
        orow[i] = __float2bfloat16(xr[i] * scale * ldf(wgt, woff + i, bf));
}

// ---------------------------------------------------------------------------
// Depthwise causal conv (K=4) + SiLU. xc = cols [0,DI) of xz16 (stride 2*DI).
// ---------------------------------------------------------------------------
__global__ __launch_bounds__(256) void conv_silu_k(const bf16* __restrict__ xz,
    const void* __restrict__ cw, long cwoff, const void* __restrict__ cb, long cboff,
    bf16* __restrict__ out, const int* __restrict__ flagp)
{
    const int bf = *flagp;
    const int idx = blockIdx.x * 256 + threadIdx.x;
    const int c = idx & (DI_ - 1);
    const int l = (idx >> 11) & (L_ - 1);
    const int b = idx >> 21;
    float acc = ldf(cb, cboff + c, bf);
    #pragma unroll
    for (int j = 0; j < KC_; ++j) {
        const int ls = l - (KC_ - 1) + j;
        if (ls >= 0)
            acc = fmaf(b2f(xz[((size_t)(b * L_ + ls)) * (2 * DI_) + c]),
                       ldf(cw, cwoff + j * DI_ + c, bf), acc);
    }
    out[idx] = __float2bfloat16(silu_f(acc));
}

// ---------------------------------------------------------------------------
// Mamba selective scan — chunk-parallel + XCD swizzle (see round 5 notes).
// ---------------------------------------------------------------------------
#define MS_NCH 16
#define MS_CH  (L_ / MS_NCH)   // 64

__global__ __launch_bounds__(256) void mamba_scan_k(
    const bf16* __restrict__ u, const bf16* __restrict__ dlt,
    const float* __restrict__ xdbl, bf16* __restrict__ xz,
    const void* __restrict__ Alog, long aoff, const void* __restrict__ Dp, long doff,
    const int* __restrict__ flagp)
{
    const int bf = *flagp;
    const int bid = ((blockIdx.x & 7) << 9) | (blockIdx.x >> 3);  // XCD swizzle, B*DI = 4096
    const int d = bid & (DI_ - 1);
    const int b = bid >> 11;
    const int s = threadIdx.x & (DS_ - 1);
    const int c = threadIdx.x >> 4;        // chunk 0..15
    const float Av = -__expf(ldf(Alog, aoff + d * DS_ + s, bf));
    const float Dv = ldf(Dp, doff + d, bf);

    __shared__ float Pl[MS_NCH][DS_];
    __shared__ float Sl[MS_NCH][DS_];

    const int l0 = c * MS_CH;

    // pass 1: chunk-local (P, S)
    float P = 1.f, S = 0.f;
    for (int i = 0; i < MS_CH; ++i) {
        const size_t row = (size_t)(b * L_ + l0 + i);
        const float ut = b2f(u[row * DI_ + d]);
        const float dt = b2f(dlt[row * DI_ + d]);
        const float Bv = xdbl[row * 96 + 64 + s];
        const float dA = __expf(dt * Av);
        P *= dA;
        S = fmaf(S, dA, dt * ut * Bv);
    }
    Pl[c][s] = P; Sl[c][s] = S;
    __syncthreads();

    // prefix combine: h at this chunk's start
    float hs = 0.f;
    for (int cc = 0; cc < c; ++cc) hs = fmaf(hs, Pl[cc][s], Sl[cc][s]);

    // pass 2: rescan with true h0, reduce over s, write y
    for (int i = 0; i < MS_CH; ++i) {
        const size_t row = (size_t)(b * L_ + l0 + i);
        const float ut = b2f(u[row * DI_ + d]);
        const float dt = b2f(dlt[row * DI_ + d]);
        const float Bv = xdbl[row * 96 + 64 + s];
        const float Cv = xdbl[row * 96 + 80 + s];
        const float dA = __expf(dt * Av);
        hs = fmaf(hs, dA, dt * ut * Bv);
        float yp = hs * Cv;
        yp += __shfl_xor(yp, 1, 16);
        yp += __shfl_xor(yp, 2, 16);
        yp += __shfl_xor(yp, 4, 16);
        yp += __shfl_xor(yp, 8, 16);
        if (s == 0) {
            const float z = b2f(xz[row * (2 * DI_) + DI_ + d]);
            xz[row * (2 * DI_) + d] = __float2bfloat16((yp + Dv * ut) * silu_f(z));
        }
    }
}

// ---------------------------------------------------------------------------
__global__ __launch_bounds__(256) void rwkv_mix_k(const bf16* __restrict__ xn,
    const void* __restrict__ mu, long muoff, bf16* __restrict__ o0,
    bf16* __restrict__ o1, bf16* __restrict__ o2, const int* __restrict__ flagp)
{
    const int bf = *flagp;
    const int idx = blockIdx.x * 256 + threadIdx.x;
    const int d = idx & (D_ - 1);
    const int l = (idx >> 10) & (L_ - 1);
    const float cur = b2f(xn[idx]);
    const float prev = (l > 0) ? b2f(xn[idx - D_]) : 0.f;
    const float m0 = ldf(mu, muoff + d, bf);
    const float m1 = ldf(mu, muoff + D_ + d, bf);
    const float m2 = ldf(mu, muoff + 2 * D_ + d, bf);
    o0[idx] = __float2bfloat16(cur * m0 + prev * (1.f - m0));
    o1[idx] = __float2bfloat16(cur * m1 + prev * (1.f - m1));
    o2[idx] = __float2bfloat16(cur * m2 + prev * (1.f - m2));
}

// ---------------------------------------------------------------------------
// RWKV scan — chunk-parallel + XCD swizzle (see round 5 notes).
// ---------------------------------------------------------------------------
#define RW_NCH 16
#define RW_CH  (L_ / RW_NCH)   // 64

__global__ __launch_bounds__(1024) void rwkv_scan_k(const bf16* __restrict__ R,
    const bf16* __restrict__ Kb, const bf16* __restrict__ V,
    const void* __restrict__ wlog, long woff, const void* __restrict__ uu, long uoff,
    bf16* __restrict__ Y, const int* __restrict__ flagp)
{
    const int bf = *flagp;
    const int bid = ((blockIdx.x & 7) << 8) | (blockIdx.x >> 3);  // XCD swizzle, B*HR*DHR = 2048
    const int v = bid & (DHR_ - 1);
    const int h = (bid >> 6) & (HR_ - 1);
    const int b = bid >> 10;
    const int k = threadIdx.x & 63;
    const int c = threadIdx.x >> 6;       // chunk 0..15
    const float ew = __expf(ldf(wlog, woff + h * DHR_ + k, bf));
    const float w  = __expf(-ew);
    const float wC = __expf(-ew * (float)RW_CH);   // w^CH
    const float uv = ldf(uu, uoff + h * DHR_ + k, bf);

    __shared__ float Se[RW_NCH][64];

    const int l0 = c * RW_CH;

    // pass 1: chunk-local S_end (S0 = 0)
    float S = 0.f;
    for (int i = 0; i < RW_CH; ++i) {
        const size_t off = ((size_t)(b * L_ + l0 + i)) * D_ + h * DHR_;
        const float kk = b2f(Kb[off + k]);
        const float vt = b2f(V[off + v]);
        S = fmaf(w, S, kk * vt);
    }
    Se[c][k] = S;
    __syncthreads();

    // prefix: S at this chunk's start
    S = 0.f;
    for (int cc = 0; cc < c; ++cc) S = fmaf(wC, S, Se[cc][k]);

    // pass 2: rescan with true S0, reduce over k, write y
    for (int i = 0; i < RW_CH; ++i) {
        const size_t off = ((size_t)(b * L_ + l0 + i)) * D_ + h * DHR_;
        const float r  = b2f(R[off + k]);
        const float kk = b2f(Kb[off + k]);
        const float vt = b2f(V[off + v]);
        const float kv = kk * vt;
        float yp = r * fmaf(uv, kv, S);
        S = fmaf(w, S, kv);
        yp += __shfl_xor(yp, 1);
        yp += __shfl_xor(yp, 2);
        yp += __shfl_xor(yp, 4);
        yp += __shfl_xor(yp, 8);
        yp += __shfl_xor(yp, 16);
        yp += __shfl_xor(yp, 32);
        if (k == 0) Y[off + v] = __float2bfloat16(yp);
    }
}

// ---------------------------------------------------------------------------
// MHA flash attention — MFMA version (see round 4 notes).
// ---------------------------------------------------------------------------
#define LDK 40   // Ks row pitch (bf16): 80B, 16B-aligned, 2-way banks (free)
#define LDV 72   // Vt/Ps row pitch (bf16): 144B, 16B-aligned, 2-way banks

__global__ __launch_bounds__(256) void mha_attn_k(const bf16* __restrict__ Q,
    const bf16* __restrict__ Kx, const bf16* __restrict__ V, bf16* __restrict__ O)
{
    const int b = blockIdx.z, h = blockIdx.y;
    const int qt = blockIdx.x;            // 0..15
    const int tid = threadIdx.x;
    const int lane = tid & 63;
    const int wid = tid >> 6;

    __shared__ __align__(16) short Ks[64 * LDK];
    __shared__ __align__(16) short Vt[32 * LDV];
    __shared__ __align__(16) short Ps[4][16 * LDV];

    const int fc  = lane & 15;            // A-row / B-col within fragment
    const int g   = lane >> 4;            // k-octet group; C rows = g*4+j
    const int fk8 = g << 3;               // 0,8,16,24

    const int q0 = qt * 64 + wid * 16;

    // Q fragment (K=32 = full head dim), loaded once
    const size_t qoff = ((size_t)(b * L_ + q0 + fc)) * D_ + h * DHA_ + fk8;
    const short8v qf = *(const short8v*)((const unsigned short*)Q + qoff);

    float4v o0 = {}, o1 = {};
    float m[4] = {-1e30f, -1e30f, -1e30f, -1e30f};
    float l[4] = {0.f, 0.f, 0.f, 0.f};
    const float scale = 0.1767766952966369f;   // 1/sqrt(32)

    // staging indices: thread t covers (row=t>>2, d-octet=(t&3)*8)
    const int sr = tid >> 2;
    const int sc = (tid & 3) << 3;

    for (int kt = 0; kt < L_; kt += 64) {
        __syncthreads();   // all waves done reading previous Ks/Vt
        {
            const size_t koff = ((size_t)(b * L_ + kt + sr)) * D_ + h * DHA_ + sc;
            const short8v k8 = *(const short8v*)((const unsigned short*)Kx + koff);
            *(short8v*)&Ks[sr * LDK + sc] = k8;
            const short8v v8 = *(const short8v*)((const unsigned short*)V + koff);
            #pragma unroll
            for (int j = 0; j < 8; ++j)
                Vt[(sc + j) * LDV + sr] = v8[j];
        }
        __syncthreads();

        // ---- QK^T: 4 mfma over 4 kv-16 sub-tiles ----
        float4v sv[4];
        #pragma unroll
        for (int nt = 0; nt < 4; ++nt) {
            const short8v kf = *(const short8v*)&Ks[(nt * 16 + fc) * LDK + fk8];
            float4v z = {};
            sv[nt] = __builtin_amdgcn_mfma_f32_16x16x32_bf16(qf, kf, z, 0, 0, 0);
        }

        // ---- online softmax (rows g*4+j, cols nt*16+fc) ----
        #pragma unroll
        for (int j = 0; j < 4; ++j) {
            float mt = fmaxf(fmaxf(sv[0][j], sv[1][j]), fmaxf(sv[2][j], sv[3][j])) * scale;
            #pragma unroll
            for (int msk = 1; msk < 16; msk <<= 1) mt = fmaxf(mt, __shfl_xor(mt, msk));
            const float mn = fmaxf(m[j], mt);
            const float corr = __expf(m[j] - mn);
            m[j] = mn;
            float sum = 0.f;
            #pragma unroll
            for (int nt = 0; nt < 4; ++nt) {
                const float p = __expf(fmaf(sv[nt][j], scale, -mn));
                sum += p;
                Ps[wid][(g * 4 + j) * LDV + nt * 16 + fc] = (short)f2bfbits(p);
            }
            #pragma unroll
            for (int msk = 1; msk < 16; msk <<= 1) sum += __shfl_xor(sum, msk);
            l[j] = l[j] * corr + sum;
            o0[j] *= corr;
            o1[j] *= corr;
        }

        // ---- PV: O += P(16x64) . V(64x32), 2 k-chunks x 2 d-tiles ----
        #pragma unroll
        for (int kc = 0; kc < 2; ++kc) {
            const short8v pf = *(const short8v*)&Ps[wid][fc * LDV + kc * 32 + fk8];
            const short8v v0 = *(const short8v*)&Vt[(fc) * LDV + kc * 32 + fk8];
            const short8v v1 = *(const short8v*)&Vt[(16 + fc) * LDV + kc * 32 + fk8];
            o0 = __builtin_amdgcn_mfma_f32_16x16x32_bf16(pf, v0, o0, 0, 0, 0);
            o1 = __builtin_amdgcn_mfma_f32_16x16x32_bf16(pf, v1, o1, 0, 0, 0);
        }
    }

    // ---- epilogue ----
    #pragma unroll
    for (int j = 0; j < 4; ++j) {
        const float inv = 1.f / l[j];
        const size_t ooff = ((size_t)(b * L_ + q0 + g * 4 + j)) * D_ + h * DHA_;
        O[ooff + fc]      = __float2bfloat16(o0[j] * inv);
        O[ooff + 16 + fc] = __float2bfloat16(o1[j] * inv);
    }
}

// ---------------------------------------------------------------------------
// Final: logits = [m,r,t] @ f_W + f_b; softmax over 3; fp32 out.
// ---------------------------------------------------------------------------
__global__ __launch_bounds__(256) void final_k(const float* __restrict__ m,
    const float* __restrict__ r, const float* __restrict__ t,
    const void* __restrict__ fW, const void* __restrict__ fb,
    float* __restrict__ out, const int* __restrict__ flagp)
{
    const int bf = *flagp;
    const int row = blockIdx.x;
    float p0 = 0.f, p1 = 0.f, p2 = 0.f;
    for (int i = threadIdx.x; i < 3 * D_; i += 256) {
        float v;
        if (i < D_)          v = m[(size_t)row * D_ + i];
        else if (i < 2 * D_) v = r[(size_t)row * D_ + i - D_];
        else                 v = t[(size_t)row * D_ + i - 2 * D_];
        p0 = fmaf(v, ldf(fW, (long)i * 3 + 0, bf), p0);
        p1 = fmaf(v, ldf(fW, (long)i * 3 + 1, bf), p1);
        p2 = fmaf(v, ldf(fW, (long)i * 3 + 2, bf), p2);
    }
    #pragma unroll
    for (int msk = 1; msk < 64; msk <<= 1) {
        p0 += __shfl_xor(p0, msk);
        p1 += __shfl_xor(p1, msk);
        p2 += __shfl_xor(p2, msk);
    }
    __shared__ float red[4][3];
    if ((threadIdx.x & 63) == 0) {
        const int w = threadIdx.x >> 6;
        red[w][0] = p0; red[w][1] = p1; red[w][2] = p2;
    }
    __syncthreads();
    if (threadIdx.x == 0) {
        const float l0 = red[0][0] + red[1][0] + red[2][0] + red[3][0] + ldf(fb, 0, bf);
        const float l1 = red[0][1] + red[1][1] + red[2][1] + red[3][1] + ldf(fb, 1, bf);
        const float l2 = red[0][2] + red[1][2] + red[2][2] + red[3][2] + ldf(fb, 2, bf);
        const float mx = fmaxf(l0, fmaxf(l1, l2));
        const float e0 = __expf(l0 - mx), e1 = __expf(l1 - mx), e2 = __expf(l2 - mx);
        const float inv = 1.f / (e0 + e1 + e2);
        out[row * 3 + 0] = e0 * inv;
        out[row * 3 + 1] = e1 * inv;
        out[row * 3 + 2] = e2 * inv;
    }
}

// ---------------------------------------------------------------------------
extern "C" void kernel_launch(void* const* d_in, const int* in_sizes, int n_in,
                              void* d_out, int out_size, void* d_ws, size_t ws_size,
                              hipStream_t stream)
{
    float* out = (float*)d_out;

    // ---- self-diagnosis: verify input sizes (dict order) -------------------
    static const int expected[29] = {
        2097152, 6144, 25165824, 49152, 12288, 1179648, 786432, 12288,
        196608, 12288, 12582912, 4096, 12288, 4194304, 4194304, 4194304,
        4194304, 4096, 4096, 2097152, 2048, 2097152, 2048, 2097152, 2048,
        2097152, 2048, 9216, 3 };
    int bad = (n_in == 29) ? -1 : 29;
    if (bad < 0)
        for (int i = 0; i < 29; ++i)
            if (in_sizes[i] != expected[i]) { bad = i; break; }
    if (bad >= 0) {
        diag_k<<<24, 256, 0, stream>>>(out, 1000.f + 8.f * bad);
        return;
    }

    // ---- workspace layout (unchanged footprint) ----------------------------
    const size_t REQ = 64 + 3ull * 8388608 + 8388608 + 16777216 + 8388608 + 786432;
    if (ws_size < REQ) {
        diag_k<<<24, 256, 0, stream>>>(out, 2048.f + (float)(ws_size >> 20));
        return;
    }
    char* base = (char*)d_ws;
    int*   flag = (int*)base;
    float* resM = (float*)(base + 64);
    float* resR = resM + 2097152;
    float* resT = resR + 2097152;
    float* bufN = resT + 2097152;                 // bf16 xn / bf16 delta / WT scratch (8 MB)
    bf16*  XZ16 = (bf16*)(bufN + 2097152);        // NBL*4096
    bf16*  U16  = XZ16 + (size_t)NBL * 4096;      // NBL*2048 (8 MB; doubles as WT scratch)
    float* XD   = (float*)(U16 + (size_t)NBL * 2048); // NBL*96

    // quarter views of XZ16 (NBL*1024 each, contiguous)
    bf16* q0 = XZ16;
    bf16* q1 = XZ16 + 1 * 2097152;
    bf16* q2 = XZ16 + 2 * 2097152;
    bf16* q3 = XZ16 + 3 * 2097152;
    bf16* u0 = U16;
    bf16* u1 = U16 + 2097152;
    bf16* N16 = (bf16*)bufN;                      // bf16 xn view
    bf16* WTb = (bf16*)bufN;                      // WT scratch view (when xn dead)
    bf16* WTu = (bf16*)U16;                       // WT scratch view (when u dead)

    const void* x        = d_in[0];
    const void* m_norm   = d_in[1];
    const void* m_Win    = d_in[2];
    const void* m_conv_w = d_in[3];
    const void* m_conv_b = d_in[4];
    const void* m_Wx     = d_in[5];
    const void* m_Wdt    = d_in[6];
    const void* m_bdt    = d_in[7];
    const void* m_Alog   = d_in[8];
    const void* m_D      = d_in[9];
    const void* m_Wout   = d_in[10];
    const void* r_norm   = d_in[11];
    const void* r_mu     = d_in[12];
    const void* r_Wr     = d_in[13];
    const void* r_Wk     = d_in[14];
    const void* r_Wv     = d_in[15];
    const void* r_Wo     = d_in[16];
    const void* r_wlog   = d_in[17];
    const void* r_u      = d_in[18];
    const void* a_Wq     = d_in[19];
    const void* a_bq     = d_in[20];
    const void* a_Wk     = d_in[21];
    const void* a_bk     = d_in[22];
    const void* a_Wv     = d_in[23];
    const void* a_bv     = d_in[24];
    const void* a_Wo     = d_in[25];
    const void* a_bo     = d_in[26];
    const void* f_W      = d_in[27];
    const void* f_b      = d_in[28];

    // W [K][N] slice (model dtype) -> WT bf16 [N][K]
    auto wcvt = [&](const void* W, long woff, int N, int K, bf16* WT) {
        wcvt_k<<<dim3(N / 32, K / 32), 256, 0, stream>>>(W, woff, N, K, WT, flag);
    };
    // gemm with pre-converted W (wDt=1, WT [N][K] bf16)
    auto gemmT = [&](const void* A, int lda, int aDt, const bf16* WT,
                     const void* bias, long boff, int hasBias,
                     void* C, int ldc, int cDt, int N, int K, int act, int acc) {
        if (N >= 2048 && (N & 127) == 0) {
            dim3 g(N / 128, NBL / 128);
            gemm_big_k<<<g, 256, 0, stream>>>(A, lda, aDt, WT, 0, 1, bias, boff,
                hasBias, C, ldc, cDt, N, K, act, acc, flag);
        } else {
            dim3 g((N + BN - 1) / BN, NBL / BM);
            gemm_k<<<g, 256, 0, stream>>>(A, lda, aDt, WT, 0, 1, bias, boff,
                hasBias, C, ldc, cDt, N, K, act, acc, flag);
        }
    };

    detect_k<<<1, 64, 0, stream>>>(x, flag);
    cast3_k<<<8192, 256, 0, stream>>>(x, resM, resR, resT, flag);

    // ---------------- Mamba branch ----------------
    for (int i = 0; i < NM_; ++i) {
        rmsnorm_k<<<NBL, 256, 0, stream>>>(resM, m_norm, (long)i * D_, N16, flag);
        wcvt(m_Win, (long)i * D_ * 2 * DI_, 2 * DI_, D_, WTu);        // U16 dead here
        gemmT(N16, D_, 1, WTu, nullptr, 0, 0,
              XZ16, 2 * DI_, 1, 2 * DI_, D_, 0, 0);
        conv_silu_k<<<16384, 256, 0, stream>>>(XZ16, m_conv_w, (long)i * KC_ * DI_,
                                               m_conv_b, (long)i * DI_, U16, flag);
        wcvt(m_Wx, (long)i * DI_ * 96, 96, DI_, WTb);                 // xn dead here
        gemmT(U16, DI_, 1, WTb, nullptr, 0, 0,
              XD, 96, 0, 96, DI_, 0, 0);
        // Wdt: legacy raw-W path (bufN becomes its C output; no dead WT region)
        {
            dim3 g(DI_ / 128, NBL / 128);
            gemm_big_k<<<g, 256, 0, stream>>>(XD, 96, 0, m_Wdt, (long)i * DTR_ * DI_, 0,
                m_bdt, (long)i * DI_, 1, bufN, DI_, 1, DI_, DTR_, 1 /*softplus*/, 0, flag);
        }
        mamba_scan_k<<<B_ * DI_, 256, 0, stream>>>(U16, (const bf16*)bufN, XD, XZ16,
            m_Alog, (long)i * DI_ * DS_, m_D, (long)i * DI_, flag);
        wcvt(m_Wout, (long)i * DI_ * D_, D_, DI_, WTu);               // u dead after scan
        gemmT(XZ16, 2 * DI_, 1, WTu, nullptr, 0, 0,
              resM, D_, 0, D_, DI_, 0, 1 /*acc*/);
    }

    // ---------------- RWKV branch ----------------
    for (int i = 0; i < NR_; ++i) {
        rmsnorm_k<<<NBL, 256, 0, stream>>>(resR, r_norm, (long)i * D_, N16, flag);
        rwkv_mix_k<<<8192, 256, 0, stream>>>(N16, r_mu, (long)i * 3 * D_,
                                             q0, q1, q2, flag);
        wcvt(r_Wr, (long)i * D_ * D_, D_, D_, WTb);                   // xn dead after mix
        gemmT(q0, D_, 1, WTb, nullptr, 0, 0, u0, D_, 1, D_, D_, 0, 0);
        wcvt(r_Wk, (long)i * D_ * D_, D_, D_, WTb);
        gemmT(q1, D_, 1, WTb, nullptr, 0, 0, u1, D_, 1, D_, D_, 0, 0);
        wcvt(r_Wv, (long)i * D_ * D_, D_, D_, WTb);
        gemmT(q2, D_, 1, WTb, nullptr, 0, 0, q3, D_, 1, D_, D_, 0, 0);
        rwkv_scan_k<<<B_ * HR_ * DHR_, RW_NCH * 64, 0, stream>>>(u0, u1, q3,
            r_wlog, (long)i * HR_ * DHR_, r_u, (long)i * HR_ * DHR_, q0, flag);
        wcvt(r_Wo, (long)i * D_ * D_, D_, D_, WTb);
        gemmT(q0, D_, 1, WTb, nullptr, 0, 0, resR, D_, 0, D_, D_, 0, 1);
    }

    // ---------------- MHA branch (no norm, no residual) ----------------
    for (int i = 0; i < NT_; ++i) {
        wcvt(a_Wq, (long)i * D_ * HA_ * DHA_, HA_ * DHA_, D_, WTb);   // bufN fully dead
        gemmT(resT, D_, 0, WTb, a_bq, (long)i * HA_ * DHA_, 1,
              u0, D_, 1, D_, D_, 0, 0);
        wcvt(a_Wk, (long)i * D_ * HA_ * DHA_, HA_ * DHA_, D_, WTb);
        gemmT(resT, D_, 0, WTb, a_bk, (long)i * HA_ * DHA_, 1,
              u1, D_, 1, D_, D_, 0, 0);
        wcvt(a_Wv, (long)i * D_ * HA_ * DHA_, HA_ * DHA_, D_, WTb);
        gemmT(resT, D_, 0, WTb, a_bv, (long)i * HA_ * DHA_, 1,
              q3, D_, 1, D_, D_, 0, 0);
        mha_attn_k<<<dim3(L_ / 64, HA_, B_), 256, 0, stream>>>(u0, u1, q3, q0);
        wcvt(a_Wo, (long)i * HA_ * DHA_ * D_, D_, HA_ * DHA_, WTb);
        gemmT(q0, D_, 1, WTb, a_bo, (long)i * D_, 1,
              resT, D_, 0, D_, HA_ * DHA_, 0, 0 /*no residual*/);
    }

    // ---------------- combine + softmax ----------------
    final_k<<<NBL, 256, 0, stream>>>(resM, resR, resT, f_W, f_b, out, flag);
}